// Round 8
// baseline (737.475 us; speedup 1.0000x reference)
//
#include <hip/hip_runtime.h>
#include <hip/hip_bf16.h>

#define TPB 256
#define STPB 512

typedef float f32x4 __attribute__((ext_vector_type(4)));
typedef short s16x8 __attribute__((ext_vector_type(8)));

static constexpr int B_ = 32;
static constexpr int C_ = 128;
static constexpr int N_ = 1024;
static constexpr int K_ = 9;
static constexpr int CN_ = C_ * N_;
static constexpr float INFV = 1.0e10f;
static constexpr float EPS_ = 1e-8f;

// ws layout (float slots), total 7,258,112 floats = 29.0 MB
static constexpr size_t XNT_OFF = 0;                             // xnt [B][N][C] fp32
static constexpr size_t XNB_OFF = (size_t)B_ * CN_;              // xnb [B][N][C] bf16 (xtb aliases later)
static constexpr size_t WBH_OFF = XNB_OFF + (size_t)B_ * CN_ / 2;
static constexpr size_t WBL_OFF = WBH_OFF + (size_t)K_ * C_ * C_ / 2;
static constexpr size_t CI_OFF  = WBL_OFF + (size_t)K_ * C_ * C_ / 2;  // [B][N][16] int
static constexpr size_t IDX_OFF = CI_OFF + (size_t)B_ * N_ * 16;       // [B][N][9] int

__device__ __forceinline__ void gload_lds16(const void* g, void* l) {
    __builtin_amdgcn_global_load_lds((const __attribute__((address_space(1))) void*)g,
                                     (__attribute__((address_space(3))) void*)l, 16, 0, 0);
}

// exact stable top-insert: beats slot p if (v > val) or (v == val and smaller idx)
#define INSERT9(Vv, Ii, vexpr, gmexpr)                                      \
    {                                                                       \
        float _v = (vexpr); int _gm = (gmexpr);                             \
        bool bp[9];                                                         \
        _Pragma("unroll")                                                   \
        for (int _p = 0; _p < 9; ++_p)                                      \
            bp[_p] = (_v > Vv[_p]) || (_v == Vv[_p] && _gm < Ii[_p]);       \
        if (bp[8]) {                                                        \
            _Pragma("unroll")                                               \
            for (int _p = 8; _p >= 1; --_p) {                               \
                Vv[_p] = bp[_p - 1] ? Vv[_p - 1] : (bp[_p] ? _v  : Vv[_p]); \
                Ii[_p] = bp[_p - 1] ? Ii[_p - 1] : (bp[_p] ? _gm : Ii[_p]); \
            }                                                               \
            if (bp[0]) { Vv[0] = _v; Ii[0] = _gm; }                         \
        }                                                                   \
    }

#define INSERT16(Vv, Ii, vexpr, gmexpr)                                     \
    {                                                                       \
        float _v = (vexpr); int _gm = (gmexpr);                             \
        bool bp[16];                                                        \
        _Pragma("unroll")                                                   \
        for (int _p = 0; _p < 16; ++_p)                                     \
            bp[_p] = (_v > Vv[_p]) || (_v == Vv[_p] && _gm < Ii[_p]);       \
        if (bp[15]) {                                                       \
            _Pragma("unroll")                                               \
            for (int _p = 15; _p >= 1; --_p) {                              \
                Vv[_p] = bp[_p - 1] ? Vv[_p - 1] : (bp[_p] ? _v  : Vv[_p]); \
                Ii[_p] = bp[_p - 1] ? Ii[_p - 1] : (bp[_p] ? _gm : Ii[_p]); \
            }                                                               \
            if (bp[0]) { Vv[0] = _v; Ii[0] = _gm; }                         \
        }                                                                   \
    }

// ---------------------------------------------------------------------------
// 1) normtrans: xnt[b][n][c] = x[b][c][n]/(||x[:,n]||+eps) fp32; xnb = bf16(same)
//    norm sum ascending-c, per-element fp32 divide: same rounding as r2-r7.
// ---------------------------------------------------------------------------
__global__ __launch_bounds__(TPB) void normtrans_kernel(const float* __restrict__ x,
                                                        float* __restrict__ xnt,
                                                        __hip_bfloat16* __restrict__ xnb) {
    __shared__ float lds[128][65];
    __shared__ float nrm[64];
    int b = blockIdx.x >> 4, n0 = (blockIdx.x & 15) << 6;
    const float* src = x + (size_t)b * CN_ + n0;
    #pragma unroll 4
    for (int i = 0; i < 32; ++i) {
        int flat = i * TPB + threadIdx.x;
        int c = flat >> 6, nn = flat & 63;
        lds[c][nn] = src[(size_t)c * N_ + nn];
    }
    __syncthreads();
    if (threadIdx.x < 64) {
        float ss = 0.f;
        #pragma unroll 8
        for (int c = 0; c < C_; ++c) { float v = lds[c][threadIdx.x]; ss += v * v; }
        nrm[threadIdx.x] = sqrtf(ss) + EPS_;
    }
    __syncthreads();
    float* dstf = xnt + ((size_t)b * N_ + n0) * C_;
    __hip_bfloat16* dstb = xnb + ((size_t)b * N_ + n0) * C_;
    #pragma unroll 4
    for (int i = 0; i < 32; ++i) {
        int flat = i * TPB + threadIdx.x;
        int nn = flat >> 7, c = flat & 127;
        float v = lds[c][nn] / nrm[nn];
        dstf[(size_t)nn * C_ + c] = v;
        dstb[(size_t)nn * C_ + c] = __float2bfloat16(v);
    }
}

// ---------------------------------------------------------------------------
// 2) xtb[b][n][c] = bf16(x[b][c][n])   (raw features for conv gather)
// ---------------------------------------------------------------------------
__global__ __launch_bounds__(TPB) void transpose_bf16_kernel(const float* __restrict__ x,
                                                             __hip_bfloat16* __restrict__ xtb) {
    __shared__ float lds[128][65];
    int b = blockIdx.x >> 4, n0 = (blockIdx.x & 15) << 6;
    const float* src = x + (size_t)b * CN_ + n0;
    #pragma unroll 4
    for (int i = 0; i < 32; ++i) {
        int flat = i * TPB + threadIdx.x;
        int c = flat >> 6, nn = flat & 63;
        lds[c][nn] = src[(size_t)c * N_ + nn];
    }
    __syncthreads();
    __hip_bfloat16* dst = xtb + (size_t)b * CN_ + (size_t)n0 * C_;
    #pragma unroll 4
    for (int i = 0; i < 32; ++i) {
        int flat = i * TPB + threadIdx.x;
        int nn = flat >> 7, c = flat & 127;
        dst[(size_t)nn * C_ + c] = __float2bfloat16(lds[c][nn]);
    }
}

// ---------------------------------------------------------------------------
// 3) split-bf16 weights: wh/wl [k][o][c]
// ---------------------------------------------------------------------------
__global__ __launch_bounds__(TPB) void wbprep_kernel(const float* __restrict__ W,
                                                     __hip_bfloat16* __restrict__ wh,
                                                     __hip_bfloat16* __restrict__ wl) {
    int t = blockIdx.x * TPB + threadIdx.x;
    int k = t / (C_ * C_);
    int r = t - k * (C_ * C_);
    int o = r >> 7, c = r & 127;
    float w = W[((size_t)o * C_ + c) * K_ + k];
    __hip_bfloat16 h = __float2bfloat16(w);
    wh[t] = h;
    wl[t] = __float2bfloat16(w - __bfloat162float(h));
}

// ---------------------------------------------------------------------------
// 4) phase-1: bf16 MFMA sim tiles + approx top-16 per row
//    block = (b, it): 128 rows x all 1024 cols (8 m-tiles).
//    Frag indexing copied from the validated conv_mfma kernel.
// ---------------------------------------------------------------------------
__global__ __launch_bounds__(STPB) void sim_mfma_topk_kernel(const __hip_bfloat16* __restrict__ xnb,
                                                             int* __restrict__ ci) {
    __shared__ __align__(16) __hip_bfloat16 Ab[2][128 * 64];   // rows, 2 c-halves, swizzled
    __shared__ __align__(16) __hip_bfloat16 Bb[2][128 * 64];   // cols, 2 c-halves, swizzled
    __shared__ float scanb[128 * 132];                          // sim tile [128][132]
    __shared__ float mvv[128][16];
    __shared__ int   mii[128][16];

    const int tid = threadIdx.x;
    const int lane = tid & 63;
    const int wv = tid >> 6;                     // 0..7
    const int b  = blockIdx.x >> 3;
    const int n0 = (blockIdx.x & 7) << 7;
    const __hip_bfloat16* xb = xnb + (size_t)b * CN_;
    const int l15 = lane & 15, l7 = lane & 7, lq = lane >> 4;
    const int swz = ((lane & 7) ^ (lane >> 3)) * 8;
    const int rl = tid >> 1;                     // scan row 0..127 (tid<256)
    const int sh = tid & 1;
    const int grow = n0 + rl;

// stage 128 tokens' 64c half hh from token base TB into linear dst (pre-swizzled src)
#define STAGE_HALF(DST, TB, HH)                                            \
    {                                                                      \
        _Pragma("unroll")                                                  \
        for (int p_ = 0; p_ < 2; ++p_) {                                   \
            int r0_ = 16 * wv + 8 * p_;                                    \
            int tok_ = (TB) + r0_ + (lane >> 3);                           \
            gload_lds16(xb + (size_t)tok_ * C_ + (HH) * 64 + swz,          \
                        (DST) + r0_ * 64);                                 \
        }                                                                  \
    }

    STAGE_HALF(&Ab[0][0], n0, 0)
    STAGE_HALF(&Ab[1][0], n0, 1)
    STAGE_HALF(&Bb[0][0], 0, 0)
    STAGE_HALF(&Bb[1][0], 0, 1)
    __syncthreads();                             // A + B(0) ready

    // A-fragments: constant across all m-tiles (wave owns rows 16wv..16wv+15)
    s16x8 af[2][2];
    #pragma unroll
    for (int h = 0; h < 2; ++h)
        #pragma unroll
        for (int kc = 0; kc < 2; ++kc)
            af[h][kc] = *(const s16x8*)&Ab[h][(16 * wv + l15) * 64 + (((kc * 4 + lq) ^ l7) << 3)];

    float val[16]; int id[16];
    #pragma unroll
    for (int p = 0; p < 16; ++p) { val[p] = -1e30f; id[p] = -1; }

    #pragma unroll 1
    for (int mt = 0; mt < 8; ++mt) {
        const int m0 = mt << 7;
        f32x4 acc[8];
        #pragma unroll
        for (int nt = 0; nt < 8; ++nt) acc[nt] = (f32x4){0.f, 0.f, 0.f, 0.f};

        #pragma unroll
        for (int h = 0; h < 2; ++h)
            #pragma unroll
            for (int kc = 0; kc < 2; ++kc) {
                const int phys = ((kc * 4 + lq) ^ l7) << 3;
                #pragma unroll
                for (int nt = 0; nt < 8; ++nt) {
                    s16x8 bb = *(const s16x8*)&Bb[h][(16 * nt + l15) * 64 + phys];
                    acc[nt] = __builtin_amdgcn_mfma_f32_16x16x32_bf16(af[h][kc], bb, acc[nt], 0, 0, 0);
                }
            }
        __syncthreads();                         // all MFMA reads of Bb done

        if (mt < 7) {                            // overwrite Bb with next col-tile
            STAGE_HALF(&Bb[0][0], m0 + 128, 0)
            STAGE_HALF(&Bb[1][0], m0 + 128, 1)
        }
        // dump sims: C layout col=lane&15 (B-row=m), row=(lane>>4)*4+r (A-row=n)
        #pragma unroll
        for (int nt = 0; nt < 8; ++nt)
            #pragma unroll
            for (int r = 0; r < 4; ++r)
                scanb[(16 * wv + 4 * lq + r) * 132 + 16 * nt + l15] = acc[nt][r];
        __syncthreads();                         // dump visible; gll drained (next Bb ready)

        if (tid < 256) {                         // 2 threads/row, 64 cols each
            float lv[16]; int li[16];
            #pragma unroll
            for (int p = 0; p < 16; ++p) { lv[p] = -1e30f; li[p] = -1; }
            const float* srow = &scanb[rl * 132 + (sh << 6)];
            const int colbase = m0 + (sh << 6);
            for (int q = 0; q < 16; ++q) {
                float4 v4 = *(const float4*)(srow + 4 * q);
                const int gm0 = colbase + 4 * q;
                float mx = fmaxf(fmaxf(v4.x, v4.y), fmaxf(v4.z, v4.w));
                bool diag = ((unsigned)(grow - gm0) < 4u);
                if (mx < lv[15] && !diag) continue;
                float vv[4] = {v4.x, v4.y, v4.z, v4.w};
                #pragma unroll
                for (int j = 0; j < 4; ++j) {
                    float v = vv[j]; int gm = gm0 + j;
                    if (gm == grow) v = INFV;    // self always a candidate
                    INSERT16(lv, li, v, gm)
                }
            }
            if (sh) {
                #pragma unroll
                for (int p = 0; p < 16; ++p) { mvv[rl][p] = lv[p]; mii[rl][p] = li[p]; }
            } else {
                #pragma unroll
                for (int p = 0; p < 16; ++p) INSERT16(val, id, lv[p], li[p])
            }
        }
        __syncthreads();                         // mvv settled; scanb reads done
        if (tid < 256 && sh == 0) {
            #pragma unroll
            for (int p = 0; p < 16; ++p) INSERT16(val, id, mvv[rl][p], mii[rl][p])
        }
        __syncthreads();                         // merge done before next dump/mvv write
    }

    if (tid < 256 && sh == 0) {
        int* op = ci + ((size_t)b * N_ + grow) * 16;
        #pragma unroll
        for (int p = 0; p < 16; ++p) op[p] = id[p];
    }
#undef STAGE_HALF
}

// ---------------------------------------------------------------------------
// 5) rescore: exact fp32 dots of the 16 candidates -> stable top-9 indices
//    16 lanes per row; candidate vectors from xnt (L2/L3 resident)
// ---------------------------------------------------------------------------
__global__ __launch_bounds__(TPB) void rescore_kernel(const float* __restrict__ xnt,
                                                      const int* __restrict__ ci,
                                                      int* __restrict__ idxo) {
    const int tid = threadIdx.x;
    const int g = tid >> 4, l = tid & 15;
    const size_t row = (size_t)blockIdx.x * 16 + g;       // global row 0..32767
    const int nrow = (int)(row & (N_ - 1));               // token index within batch
    const float* xbase = xnt + (row >> 10) * (size_t)CN_; // batch base
    const float* rvp = xbase + (size_t)nrow * C_;

    float rv[8];
    #pragma unroll
    for (int t = 0; t < 8; ++t) rv[t] = rvp[t * 16 + l];

    float val[9]; int id[9];
    #pragma unroll
    for (int p = 0; p < 9; ++p) { val[p] = -1e30f; id[p] = -1; }

    const int* cp = ci + row * 16;
    #pragma unroll 1
    for (int j = 0; j < 16; ++j) {
        int cand = cp[j];
        const float* cv = xbase + (size_t)cand * C_;
        float s = 0.f;
        #pragma unroll
        for (int t = 0; t < 8; ++t) s = fmaf(rv[t], cv[t * 16 + l], s);
        #pragma unroll
        for (int d = 1; d < 16; d <<= 1) s += __shfl_xor(s, d);
        float v = (cand == nrow) ? INFV : s;
        INSERT9(val, id, v, cand)
    }
    if (l == 0) {
        int* op = idxo + row * 9;
        #pragma unroll
        for (int p = 0; p < 9; ++p) op[p] = id[p];
    }
}

// ---------------------------------------------------------------------------
// 6) MFMA conv (unchanged from r4-r7, passing): 128o x 128n per block
// ---------------------------------------------------------------------------
__global__ __launch_bounds__(TPB) void conv_mfma_kernel(const __hip_bfloat16* __restrict__ xtb,
                                                        const __hip_bfloat16* __restrict__ wbh,
                                                        const __hip_bfloat16* __restrict__ wbl,
                                                        const int* __restrict__ idxi,
                                                        float* __restrict__ out) {
    __shared__ __align__(16) __hip_bfloat16 gbuf[2][128 * 64];
    __shared__ __align__(16) __hip_bfloat16 hbuf[2][128 * 64];
    __shared__ __align__(16) __hip_bfloat16 lbuf[2][128 * 64];
    __shared__ int ids[K_ * 128];

    const int tid = threadIdx.x;
    const int lane = tid & 63;
    const int wv = tid >> 6;
    const int b  = blockIdx.x >> 3;
    const int n0 = (blockIdx.x & 7) << 7;
    const __hip_bfloat16* xb = xtb + (size_t)b * CN_;

    for (int j = tid; j < K_ * 128; j += TPB) {
        int k = j >> 7, r = j & 127;
        ids[j] = idxi[((size_t)b * N_ + n0 + r) * K_ + k];
    }
    __syncthreads();

    f32x4 acc[2][8];
    #pragma unroll
    for (int mt = 0; mt < 2; ++mt)
        #pragma unroll
        for (int nt = 0; nt < 8; ++nt) acc[mt][nt] = (f32x4){0.f, 0.f, 0.f, 0.f};

    const int swz = ((lane & 7) ^ (lane >> 3)) * 8;

#define CONV_STAGE(S, PB)                                                               \
    {                                                                                   \
        const int k_ = (S) >> 1, ch_ = ((S) & 1) * 64;                                  \
        _Pragma("unroll")                                                               \
        for (int q_ = 0; q_ < 4; ++q_) {                                                \
            int row_ = 32 * wv + 8 * q_ + (lane >> 3);                                  \
            int tok_ = ids[k_ * 128 + row_];                                            \
            gload_lds16(xb + (size_t)tok_ * C_ + ch_ + swz, &gbuf[PB][(32 * wv + 8 * q_) * 64]); \
            const size_t wr_ = ((size_t)k_ * 128 + row_) * C_ + ch_ + swz;              \
            gload_lds16(wbh + wr_, &hbuf[PB][(32 * wv + 8 * q_) * 64]);                 \
            gload_lds16(wbl + wr_, &lbuf[PB][(32 * wv + 8 * q_) * 64]);                 \
        }                                                                               \
    }

    CONV_STAGE(0, 0)
    __syncthreads();

    const int l15 = lane & 15, l7 = lane & 7, lq = lane >> 4;
    int pb = 0;
    #pragma unroll 1
    for (int s = 0; s < 18; ++s) {
        if (s < 17) CONV_STAGE(s + 1, pb ^ 1)
        const __hip_bfloat16* G = gbuf[pb];
        const __hip_bfloat16* H = hbuf[pb];
        const __hip_bfloat16* L = lbuf[pb];
        #pragma unroll
        for (int kc = 0; kc < 2; ++kc) {
            const int phys = ((kc * 4 + lq) ^ l7) * 8;
            s16x8 bb[8];
            #pragma unroll
            for (int nt = 0; nt < 8; ++nt)
                bb[nt] = *(const s16x8*)&G[(16 * nt + l15) * 64 + phys];
            #pragma unroll
            for (int mt = 0; mt < 2; ++mt) {
                const int orow = (32 * wv + 16 * mt + l15) * 64 + phys;
                s16x8 ah = *(const s16x8*)&H[orow];
                s16x8 al = *(const s16x8*)&L[orow];
                #pragma unroll
                for (int nt = 0; nt < 8; ++nt) {
                    acc[mt][nt] = __builtin_amdgcn_mfma_f32_16x16x32_bf16(ah, bb[nt], acc[mt][nt], 0, 0, 0);
                    acc[mt][nt] = __builtin_amdgcn_mfma_f32_16x16x32_bf16(al, bb[nt], acc[mt][nt], 0, 0, 0);
                }
            }
        }
        __syncthreads();
        pb ^= 1;
    }

    float* ob = out + (size_t)b * CN_;
    #pragma unroll
    for (int mt = 0; mt < 2; ++mt)
        #pragma unroll
        for (int nt = 0; nt < 8; ++nt) {
            int o = 32 * wv + 16 * mt + lq * 4;
            int n = n0 + 16 * nt + l15;
            #pragma unroll
            for (int r = 0; r < 4; ++r)
                ob[(size_t)(o + r) * N_ + n] = acc[mt][nt][r];
        }
#undef CONV_STAGE
}

// ---------------------------------------------------------------------------
extern "C" void kernel_launch(void* const* d_in, const int* in_sizes, int n_in,
                              void* d_out, int out_size, void* d_ws, size_t ws_size,
                              hipStream_t stream) {
    (void)in_sizes; (void)n_in; (void)out_size; (void)ws_size;
    const float* x = (const float*)d_in[0];
    const float* W = (const float*)d_in[1];
    float* out = (float*)d_out;
    float* ws  = (float*)d_ws;

    float* xnt = ws + XNT_OFF;
    __hip_bfloat16* xnb = (__hip_bfloat16*)(ws + XNB_OFF);
    __hip_bfloat16* xtb = (__hip_bfloat16*)(ws + XNB_OFF);  // aliases xnb (disjoint lifetime)
    __hip_bfloat16* wbh = (__hip_bfloat16*)(ws + WBH_OFF);
    __hip_bfloat16* wbl = (__hip_bfloat16*)(ws + WBL_OFF);
    int* ci  = (int*)(ws + CI_OFF);
    int* idx = (int*)(ws + IDX_OFF);

    normtrans_kernel<<<B_ * 16, TPB, 0, stream>>>(x, xnt, xnb);
    wbprep_kernel<<<(K_ * C_ * C_) / TPB, TPB, 0, stream>>>(W, wbh, wbl);
    sim_mfma_topk_kernel<<<B_ * 8, STPB, 0, stream>>>(xnb, ci);
    rescore_kernel<<<(B_ * N_) / 16, TPB, 0, stream>>>(xnt, ci, idx);
    transpose_bf16_kernel<<<B_ * 16, TPB, 0, stream>>>(x, xtb);  // xnb dead now
    conv_mfma_kernel<<<B_ * 8, TPB, 0, stream>>>(xtb, wbh, wbl, idx, out);
}

// Round 9
// 390.441 us; speedup vs baseline: 1.8888x; 1.8888x over previous
//
#include <hip/hip_runtime.h>
#include <hip/hip_bf16.h>

#define TPB 256
#define STPB 512

typedef float f32x4 __attribute__((ext_vector_type(4)));
typedef short s16x8 __attribute__((ext_vector_type(8)));

static constexpr int B_ = 32;
static constexpr int C_ = 128;
static constexpr int N_ = 1024;
static constexpr int K_ = 9;
static constexpr int CN_ = C_ * N_;
static constexpr float INFV = 1.0e10f;
static constexpr float EPS_ = 1e-8f;

// ws layout (float slots)
static constexpr size_t XNT_OFF = 0;                             // xnt [B][N][C] fp32
static constexpr size_t XNB_OFF = (size_t)B_ * CN_;              // xnb [B][N][C] bf16 (xtb aliases later)
static constexpr size_t WBH_OFF = XNB_OFF + (size_t)B_ * CN_ / 2;
static constexpr size_t WBL_OFF = WBH_OFF + (size_t)K_ * C_ * C_ / 2;
static constexpr size_t CI_OFF  = WBL_OFF + (size_t)K_ * C_ * C_ / 2;  // [B][N][16] int
static constexpr size_t IDX_OFF = CI_OFF + (size_t)B_ * N_ * 16;       // [B][N][9] int

__device__ __forceinline__ void gload_lds16(const void* g, void* l) {
    __builtin_amdgcn_global_load_lds((const __attribute__((address_space(1))) void*)g,
                                     (__attribute__((address_space(3))) void*)l, 16, 0, 0);
}

// exact stable top-insert: beats slot p if (v > val) or (v == val and smaller idx)
#define INSERT9(Vv, Ii, vexpr, gmexpr)                                      \
    {                                                                       \
        float _v = (vexpr); int _gm = (gmexpr);                             \
        bool bp[9];                                                         \
        _Pragma("unroll")                                                   \
        for (int _p = 0; _p < 9; ++_p)                                      \
            bp[_p] = (_v > Vv[_p]) || (_v == Vv[_p] && _gm < Ii[_p]);       \
        if (bp[8]) {                                                        \
            _Pragma("unroll")                                               \
            for (int _p = 8; _p >= 1; --_p) {                               \
                Vv[_p] = bp[_p - 1] ? Vv[_p - 1] : (bp[_p] ? _v  : Vv[_p]); \
                Ii[_p] = bp[_p - 1] ? Ii[_p - 1] : (bp[_p] ? _gm : Ii[_p]); \
            }                                                               \
            if (bp[0]) { Vv[0] = _v; Ii[0] = _gm; }                         \
        }                                                                   \
    }

#define INSERT16(Vv, Ii, vexpr, gmexpr)                                     \
    {                                                                       \
        float _v = (vexpr); int _gm = (gmexpr);                             \
        bool bp[16];                                                        \
        _Pragma("unroll")                                                   \
        for (int _p = 0; _p < 16; ++_p)                                     \
            bp[_p] = (_v > Vv[_p]) || (_v == Vv[_p] && _gm < Ii[_p]);       \
        if (bp[15]) {                                                       \
            _Pragma("unroll")                                               \
            for (int _p = 15; _p >= 1; --_p) {                              \
                Vv[_p] = bp[_p - 1] ? Vv[_p - 1] : (bp[_p] ? _v  : Vv[_p]); \
                Ii[_p] = bp[_p - 1] ? Ii[_p - 1] : (bp[_p] ? _gm : Ii[_p]); \
            }                                                               \
            if (bp[0]) { Vv[0] = _v; Ii[0] = _gm; }                         \
        }                                                                   \
    }

// ---------------------------------------------------------------------------
// 1) normtrans: xnt[b][n][c] = x[b][c][n]/(||x[:,n]||+eps) fp32; xnb = bf16(same)
// ---------------------------------------------------------------------------
__global__ __launch_bounds__(TPB) void normtrans_kernel(const float* __restrict__ x,
                                                        float* __restrict__ xnt,
                                                        __hip_bfloat16* __restrict__ xnb) {
    __shared__ float lds[128][65];
    __shared__ float nrm[64];
    int b = blockIdx.x >> 4, n0 = (blockIdx.x & 15) << 6;
    const float* src = x + (size_t)b * CN_ + n0;
    #pragma unroll 4
    for (int i = 0; i < 32; ++i) {
        int flat = i * TPB + threadIdx.x;
        int c = flat >> 6, nn = flat & 63;
        lds[c][nn] = src[(size_t)c * N_ + nn];
    }
    __syncthreads();
    if (threadIdx.x < 64) {
        float ss = 0.f;
        #pragma unroll 8
        for (int c = 0; c < C_; ++c) { float v = lds[c][threadIdx.x]; ss += v * v; }
        nrm[threadIdx.x] = sqrtf(ss) + EPS_;
    }
    __syncthreads();
    float* dstf = xnt + ((size_t)b * N_ + n0) * C_;
    __hip_bfloat16* dstb = xnb + ((size_t)b * N_ + n0) * C_;
    #pragma unroll 4
    for (int i = 0; i < 32; ++i) {
        int flat = i * TPB + threadIdx.x;
        int nn = flat >> 7, c = flat & 127;
        float v = lds[c][nn] / nrm[nn];
        dstf[(size_t)nn * C_ + c] = v;
        dstb[(size_t)nn * C_ + c] = __float2bfloat16(v);
    }
}

// ---------------------------------------------------------------------------
// 2) xtb[b][n][c] = bf16(x[b][c][n])   (raw features for conv gather)
// ---------------------------------------------------------------------------
__global__ __launch_bounds__(TPB) void transpose_bf16_kernel(const float* __restrict__ x,
                                                             __hip_bfloat16* __restrict__ xtb) {
    __shared__ float lds[128][65];
    int b = blockIdx.x >> 4, n0 = (blockIdx.x & 15) << 6;
    const float* src = x + (size_t)b * CN_ + n0;
    #pragma unroll 4
    for (int i = 0; i < 32; ++i) {
        int flat = i * TPB + threadIdx.x;
        int c = flat >> 6, nn = flat & 63;
        lds[c][nn] = src[(size_t)c * N_ + nn];
    }
    __syncthreads();
    __hip_bfloat16* dst = xtb + (size_t)b * CN_ + (size_t)n0 * C_;
    #pragma unroll 4
    for (int i = 0; i < 32; ++i) {
        int flat = i * TPB + threadIdx.x;
        int nn = flat >> 7, c = flat & 127;
        dst[(size_t)nn * C_ + c] = __float2bfloat16(lds[c][nn]);
    }
}

// ---------------------------------------------------------------------------
// 3) split-bf16 weights: wh/wl [k][o][c]
// ---------------------------------------------------------------------------
__global__ __launch_bounds__(TPB) void wbprep_kernel(const float* __restrict__ W,
                                                     __hip_bfloat16* __restrict__ wh,
                                                     __hip_bfloat16* __restrict__ wl) {
    int t = blockIdx.x * TPB + threadIdx.x;
    int k = t / (C_ * C_);
    int r = t - k * (C_ * C_);
    int o = r >> 7, c = r & 127;
    float w = W[((size_t)o * C_ + c) * K_ + k];
    __hip_bfloat16 h = __float2bfloat16(w);
    wh[t] = h;
    wl[t] = __float2bfloat16(w - __bfloat162float(h));
}

// ---------------------------------------------------------------------------
// 4) phase-1: bf16 MFMA sim + approx top-16 per row.
//    512 threads: (row = tid&127, 32-col seg = tid>>7); running top-16 across
//    all 8 col-tiles (never reset); ONE merge at the end. No spill: lb(512,1).
// ---------------------------------------------------------------------------
__global__ __launch_bounds__(STPB, 1) void sim_mfma_topk_kernel(const __hip_bfloat16* __restrict__ xnb,
                                                                int* __restrict__ ci) {
    __shared__ __align__(16) __hip_bfloat16 Ab[2][128 * 64];   // rows, 2 c-halves, swizzled
    __shared__ __align__(16) __hip_bfloat16 Bb[2][128 * 64];   // cols, 2 c-halves, swizzled
    __shared__ __align__(16) float scanb[128 * 132];           // sim tile [128][132]; final cand buf aliases

    const int tid = threadIdx.x;
    const int lane = tid & 63;
    const int wv = tid >> 6;                     // 0..7
    const int b  = blockIdx.x >> 3;
    const int n0 = (blockIdx.x & 7) << 7;
    const __hip_bfloat16* xb = xnb + (size_t)b * CN_;
    const int l15 = lane & 15, l7 = lane & 7, lq = lane >> 4;
    const int swz = ((lane & 7) ^ (lane >> 3)) * 8;
    const int srow = tid & 127;                  // owned row
    const int sseg = tid >> 7;                   // owned 32-col segment
    const int grow = n0 + srow;

// stage 128 tokens' 64c half HH from token base TB into linear dst (pre-swizzled src)
#define STAGE_HALF(DST, TB, HH)                                            \
    {                                                                      \
        _Pragma("unroll")                                                  \
        for (int p_ = 0; p_ < 2; ++p_) {                                   \
            int r0_ = 16 * wv + 8 * p_;                                    \
            int tok_ = (TB) + r0_ + (lane >> 3);                           \
            gload_lds16(xb + (size_t)tok_ * C_ + (HH) * 64 + swz,          \
                        (DST) + r0_ * 64);                                 \
        }                                                                  \
    }

    STAGE_HALF(&Ab[0][0], n0, 0)
    STAGE_HALF(&Ab[1][0], n0, 1)
    STAGE_HALF(&Bb[0][0], 0, 0)
    STAGE_HALF(&Bb[1][0], 0, 1)
    __syncthreads();                             // A + B(0) ready

    // A-fragments: constant across all m-tiles (wave owns rows 16wv..16wv+15)
    s16x8 af[2][2];
    #pragma unroll
    for (int h = 0; h < 2; ++h)
        #pragma unroll
        for (int kc = 0; kc < 2; ++kc)
            af[h][kc] = *(const s16x8*)&Ab[h][(16 * wv + l15) * 64 + (((kc * 4 + lq) ^ l7) << 3)];

    float lv[16]; int li[16];                    // running top-16, warm across all mt
    #pragma unroll
    for (int p = 0; p < 16; ++p) { lv[p] = -1e30f; li[p] = -1; }

    #pragma unroll 1
    for (int mt = 0; mt < 8; ++mt) {
        const int m0 = mt << 7;
        f32x4 acc[8];
        #pragma unroll
        for (int nt = 0; nt < 8; ++nt) acc[nt] = (f32x4){0.f, 0.f, 0.f, 0.f};

        #pragma unroll
        for (int h = 0; h < 2; ++h)
            #pragma unroll
            for (int kc = 0; kc < 2; ++kc) {
                const int phys = ((kc * 4 + lq) ^ l7) << 3;
                #pragma unroll
                for (int nt = 0; nt < 8; ++nt) {
                    s16x8 bb = *(const s16x8*)&Bb[h][(16 * nt + l15) * 64 + phys];
                    acc[nt] = __builtin_amdgcn_mfma_f32_16x16x32_bf16(af[h][kc], bb, acc[nt], 0, 0, 0);
                }
            }
        __syncthreads();                         // MFMA reads of Bb done; prev scan done

        if (mt < 7) {                            // overwrite Bb with next col-tile
            STAGE_HALF(&Bb[0][0], m0 + 128, 0)
            STAGE_HALF(&Bb[1][0], m0 + 128, 1)
        }
        // dump sims: C layout col=lane&15 (B-row=m), row=(lane>>4)*4+r (A-row=n)
        #pragma unroll
        for (int nt = 0; nt < 8; ++nt)
            #pragma unroll
            for (int r = 0; r < 4; ++r)
                scanb[(16 * wv + 4 * lq + r) * 132 + 16 * nt + l15] = acc[nt][r];
        __syncthreads();                         // dump visible; gll drained (next Bb ready)

        // scan own (row, 32-col segment), all 512 threads
        const float* sp = &scanb[srow * 132 + (sseg << 5)];
        const int cb = m0 + (sseg << 5);
        #pragma unroll 1
        for (int q = 0; q < 8; ++q) {
            float4 v4 = *(const float4*)(sp + 4 * q);
            const int gm0 = cb + 4 * q;
            float mx = fmaxf(fmaxf(v4.x, v4.y), fmaxf(v4.z, v4.w));
            bool diag = ((unsigned)(grow - gm0) < 4u);
            if (mx < lv[15] && !diag) continue;
            float vv[4] = {v4.x, v4.y, v4.z, v4.w};
            #pragma unroll
            for (int j = 0; j < 4; ++j) {
                float v = vv[j]; int gm = gm0 + j;
                if (gm == grow) v = INFV;        // self always a candidate
                INSERT16(lv, li, v, gm)
            }
        }
    }

    // final: segs 1..3 dump their lists; seg-0 thread merges once
    __syncthreads();                             // last scan done; scanb reusable
    float* fv = scanb;                           // [128][4][16] floats (slot 0 unused)
    int*   fi = (int*)(scanb + 8192);            // [128][4][16] ints
    if (sseg) {
        #pragma unroll
        for (int p = 0; p < 16; ++p) {
            int sl = ((srow << 2) + sseg) * 16 + ((p + srow) & 15);  // bank-rotated
            fv[sl] = lv[p]; fi[sl] = li[p];
        }
    }
    __syncthreads();
    if (tid < 128) {                             // sseg==0, srow==tid
        #pragma unroll 1
        for (int s = 1; s < 4; ++s)
            #pragma unroll
            for (int p = 0; p < 16; ++p) {
                int sl = ((tid << 2) + s) * 16 + ((p + tid) & 15);
                INSERT16(lv, li, fv[sl], fi[sl])
            }
        int* op = ci + ((size_t)b * N_ + grow) * 16;
        #pragma unroll
        for (int p = 0; p < 16; ++p) op[p] = li[p];
    }
#undef STAGE_HALF
}

// ---------------------------------------------------------------------------
// 5) rescore: exact fp32 dots of the 16 candidates -> stable top-9 indices
// ---------------------------------------------------------------------------
__global__ __launch_bounds__(TPB) void rescore_kernel(const float* __restrict__ xnt,
                                                      const int* __restrict__ ci,
                                                      int* __restrict__ idxo) {
    const int tid = threadIdx.x;
    const int g = tid >> 4, l = tid & 15;
    const size_t row = (size_t)blockIdx.x * 16 + g;       // global row 0..32767
    const int nrow = (int)(row & (N_ - 1));               // token index within batch
    const float* xbase = xnt + (row >> 10) * (size_t)CN_; // batch base
    const float* rvp = xbase + (size_t)nrow * C_;

    float rv[8];
    #pragma unroll
    for (int t = 0; t < 8; ++t) rv[t] = rvp[t * 16 + l];

    float val[9]; int id[9];
    #pragma unroll
    for (int p = 0; p < 9; ++p) { val[p] = -1e30f; id[p] = -1; }

    const int* cp = ci + row * 16;
    #pragma unroll 1
    for (int j = 0; j < 16; ++j) {
        int cand = cp[j];
        const float* cv = xbase + (size_t)cand * C_;
        float s = 0.f;
        #pragma unroll
        for (int t = 0; t < 8; ++t) s = fmaf(rv[t], cv[t * 16 + l], s);
        #pragma unroll
        for (int d = 1; d < 16; d <<= 1) s += __shfl_xor(s, d);
        float v = (cand == nrow) ? INFV : s;
        INSERT9(val, id, v, cand)
    }
    if (l == 0) {
        int* op = idxo + row * 9;
        #pragma unroll
        for (int p = 0; p < 9; ++p) op[p] = id[p];
    }
}

// ---------------------------------------------------------------------------
// 6) MFMA conv (unchanged, passing): 128o x 128n per block
// ---------------------------------------------------------------------------
__global__ __launch_bounds__(TPB) void conv_mfma_kernel(const __hip_bfloat16* __restrict__ xtb,
                                                        const __hip_bfloat16* __restrict__ wbh,
                                                        const __hip_bfloat16* __restrict__ wbl,
                                                        const int* __restrict__ idxi,
                                                        float* __restrict__ out) {
    __shared__ __align__(16) __hip_bfloat16 gbuf[2][128 * 64];
    __shared__ __align__(16) __hip_bfloat16 hbuf[2][128 * 64];
    __shared__ __align__(16) __hip_bfloat16 lbuf[2][128 * 64];
    __shared__ int ids[K_ * 128];

    const int tid = threadIdx.x;
    const int lane = tid & 63;
    const int wv = tid >> 6;
    const int b  = blockIdx.x >> 3;
    const int n0 = (blockIdx.x & 7) << 7;
    const __hip_bfloat16* xb = xtb + (size_t)b * CN_;

    for (int j = tid; j < K_ * 128; j += TPB) {
        int k = j >> 7, r = j & 127;
        ids[j] = idxi[((size_t)b * N_ + n0 + r) * K_ + k];
    }
    __syncthreads();

    f32x4 acc[2][8];
    #pragma unroll
    for (int mt = 0; mt < 2; ++mt)
        #pragma unroll
        for (int nt = 0; nt < 8; ++nt) acc[mt][nt] = (f32x4){0.f, 0.f, 0.f, 0.f};

    const int swz = ((lane & 7) ^ (lane >> 3)) * 8;

#define CONV_STAGE(S, PB)                                                               \
    {                                                                                   \
        const int k_ = (S) >> 1, ch_ = ((S) & 1) * 64;                                  \
        _Pragma("unroll")                                                               \
        for (int q_ = 0; q_ < 4; ++q_) {                                                \
            int row_ = 32 * wv + 8 * q_ + (lane >> 3);                                  \
            int tok_ = ids[k_ * 128 + row_];                                            \
            gload_lds16(xb + (size_t)tok_ * C_ + ch_ + swz, &gbuf[PB][(32 * wv + 8 * q_) * 64]); \
            const size_t wr_ = ((size_t)k_ * 128 + row_) * C_ + ch_ + swz;              \
            gload_lds16(wbh + wr_, &hbuf[PB][(32 * wv + 8 * q_) * 64]);                 \
            gload_lds16(wbl + wr_, &lbuf[PB][(32 * wv + 8 * q_) * 64]);                 \
        }                                                                               \
    }

    CONV_STAGE(0, 0)
    __syncthreads();

    const int l15 = lane & 15, l7 = lane & 7, lq = lane >> 4;
    int pb = 0;
    #pragma unroll 1
    for (int s = 0; s < 18; ++s) {
        if (s < 17) CONV_STAGE(s + 1, pb ^ 1)
        const __hip_bfloat16* G = gbuf[pb];
        const __hip_bfloat16* H = hbuf[pb];
        const __hip_bfloat16* L = lbuf[pb];
        #pragma unroll
        for (int kc = 0; kc < 2; ++kc) {
            const int phys = ((kc * 4 + lq) ^ l7) * 8;
            s16x8 bb[8];
            #pragma unroll
            for (int nt = 0; nt < 8; ++nt)
                bb[nt] = *(const s16x8*)&G[(16 * nt + l15) * 64 + phys];
            #pragma unroll
            for (int mt = 0; mt < 2; ++mt) {
                const int orow = (32 * wv + 16 * mt + l15) * 64 + phys;
                s16x8 ah = *(const s16x8*)&H[orow];
                s16x8 al = *(const s16x8*)&L[orow];
                #pragma unroll
                for (int nt = 0; nt < 8; ++nt) {
                    acc[mt][nt] = __builtin_amdgcn_mfma_f32_16x16x32_bf16(ah, bb[nt], acc[mt][nt], 0, 0, 0);
                    acc[mt][nt] = __builtin_amdgcn_mfma_f32_16x16x32_bf16(al, bb[nt], acc[mt][nt], 0, 0, 0);
                }
            }
        }
        __syncthreads();
        pb ^= 1;
    }

    float* ob = out + (size_t)b * CN_;
    #pragma unroll
    for (int mt = 0; mt < 2; ++mt)
        #pragma unroll
        for (int nt = 0; nt < 8; ++nt) {
            int o = 32 * wv + 16 * mt + lq * 4;
            int n = n0 + 16 * nt + l15;
            #pragma unroll
            for (int r = 0; r < 4; ++r)
                ob[(size_t)(o + r) * N_ + n] = acc[mt][nt][r];
        }
#undef CONV_STAGE
}

// ---------------------------------------------------------------------------
extern "C" void kernel_launch(void* const* d_in, const int* in_sizes, int n_in,
                              void* d_out, int out_size, void* d_ws, size_t ws_size,
                              hipStream_t stream) {
    (void)in_sizes; (void)n_in; (void)out_size; (void)ws_size;
    const float* x = (const float*)d_in[0];
    const float* W = (const float*)d_in[1];
    float* out = (float*)d_out;
    float* ws  = (float*)d_ws;

    float* xnt = ws + XNT_OFF;
    __hip_bfloat16* xnb = (__hip_bfloat16*)(ws + XNB_OFF);
    __hip_bfloat16* xtb = (__hip_bfloat16*)(ws + XNB_OFF);  // aliases xnb (disjoint lifetime)
    __hip_bfloat16* wbh = (__hip_bfloat16*)(ws + WBH_OFF);
    __hip_bfloat16* wbl = (__hip_bfloat16*)(ws + WBL_OFF);
    int* ci  = (int*)(ws + CI_OFF);
    int* idx = (int*)(ws + IDX_OFF);

    normtrans_kernel<<<B_ * 16, TPB, 0, stream>>>(x, xnt, xnb);
    wbprep_kernel<<<(K_ * C_ * C_) / TPB, TPB, 0, stream>>>(W, wbh, wbl);
    sim_mfma_topk_kernel<<<B_ * 8, STPB, 0, stream>>>(xnb, ci);
    rescore_kernel<<<(B_ * N_) / 16, TPB, 0, stream>>>(xnt, ci, idx);
    transpose_bf16_kernel<<<B_ * 16, TPB, 0, stream>>>(x, xtb);  // xnb dead now
    conv_mfma_kernel<<<B_ * 8, TPB, 0, stream>>>(xtb, wbh, wbl, idx, out);
}

// Round 10
// 161.322 us; speedup vs baseline: 4.5715x; 2.4203x over previous
//
#include <hip/hip_runtime.h>
#include <hip/hip_bf16.h>

#define TPB 256
#define STPB 512

typedef float f32x4 __attribute__((ext_vector_type(4)));
typedef short s16x8 __attribute__((ext_vector_type(8)));

static constexpr int B_ = 32;
static constexpr int C_ = 128;
static constexpr int N_ = 1024;
static constexpr int K_ = 9;
static constexpr int CN_ = C_ * N_;
static constexpr float INFV = 1.0e10f;
static constexpr float EPS_ = 1e-8f;

// ws layout (float slots)
static constexpr size_t XNT_OFF = 0;                             // xnt [B][N][C] fp32
static constexpr size_t XNB_OFF = (size_t)B_ * CN_;              // xnb [B][N][C] bf16 (xtb aliases later)
static constexpr size_t WBH_OFF = XNB_OFF + (size_t)B_ * CN_ / 2;
static constexpr size_t WBL_OFF = WBH_OFF + (size_t)K_ * C_ * C_ / 2;
static constexpr size_t CI_OFF  = WBL_OFF + (size_t)K_ * C_ * C_ / 2;  // [B][N][16] int
static constexpr size_t IDX_OFF = CI_OFF + (size_t)B_ * N_ * 16;       // [B][N][9] int

__device__ __forceinline__ void gload_lds16(const void* g, void* l) {
    __builtin_amdgcn_global_load_lds((const __attribute__((address_space(1))) void*)g,
                                     (__attribute__((address_space(3))) void*)l, 16, 0, 0);
}

// exact stable top-9 insert (rescore only)
#define INSERT9(Vv, Ii, vexpr, gmexpr)                                      \
    {                                                                       \
        float _v = (vexpr); int _gm = (gmexpr);                             \
        bool bp[9];                                                         \
        _Pragma("unroll")                                                   \
        for (int _p = 0; _p < 9; ++_p)                                      \
            bp[_p] = (_v > Vv[_p]) || (_v == Vv[_p] && _gm < Ii[_p]);       \
        if (bp[8]) {                                                        \
            _Pragma("unroll")                                               \
            for (int _p = 8; _p >= 1; --_p) {                               \
                Vv[_p] = bp[_p - 1] ? Vv[_p - 1] : (bp[_p] ? _v  : Vv[_p]); \
                Ii[_p] = bp[_p - 1] ? Ii[_p - 1] : (bp[_p] ? _gm : Ii[_p]); \
            }                                                               \
            if (bp[0]) { Vv[0] = _v; Ii[0] = _gm; }                         \
        }                                                                   \
    }

// unsorted top-16 keyset insert: replace unique min slot, recompute min tree
#define KINSERT(KEYS, THR, KEXPR)                                           \
    {                                                                       \
        unsigned _k = (KEXPR);                                              \
        if (_k > (THR)) {                                                   \
            _Pragma("unroll")                                               \
            for (int _p = 0; _p < 16; ++_p)                                 \
                KEYS[_p] = (KEYS[_p] == (THR)) ? _k : KEYS[_p];             \
            unsigned _a0 = min(KEYS[0],  KEYS[1]);                          \
            unsigned _a1 = min(KEYS[2],  KEYS[3]);                          \
            unsigned _a2 = min(KEYS[4],  KEYS[5]);                          \
            unsigned _a3 = min(KEYS[6],  KEYS[7]);                          \
            unsigned _a4 = min(KEYS[8],  KEYS[9]);                          \
            unsigned _a5 = min(KEYS[10], KEYS[11]);                         \
            unsigned _a6 = min(KEYS[12], KEYS[13]);                         \
            unsigned _a7 = min(KEYS[14], KEYS[15]);                         \
            _a0 = min(_a0, _a1); _a2 = min(_a2, _a3);                       \
            _a4 = min(_a4, _a5); _a6 = min(_a6, _a7);                       \
            _a0 = min(_a0, _a2); _a4 = min(_a4, _a6);                       \
            (THR) = min(_a0, _a4);                                          \
        }                                                                   \
    }

// monotone (value, smaller-index-wins) packed key; drops 10 low mantissa bits
__device__ __forceinline__ unsigned simkey(float v, unsigned lowfield) {
    unsigned u = __float_as_uint(v);
    u ^= ((unsigned)((int)u >> 31) | 0x80000000u);
    return (u & 0xFFFFFC00u) | lowfield;
}

// ---------------------------------------------------------------------------
// 1) normtrans: xnt[b][n][c] = x[b][c][n]/(||x[:,n]||+eps) fp32; xnb = bf16(same)
// ---------------------------------------------------------------------------
__global__ __launch_bounds__(TPB) void normtrans_kernel(const float* __restrict__ x,
                                                        float* __restrict__ xnt,
                                                        __hip_bfloat16* __restrict__ xnb) {
    __shared__ float lds[128][65];
    __shared__ float nrm[64];
    int b = blockIdx.x >> 4, n0 = (blockIdx.x & 15) << 6;
    const float* src = x + (size_t)b * CN_ + n0;
    #pragma unroll 4
    for (int i = 0; i < 32; ++i) {
        int flat = i * TPB + threadIdx.x;
        int c = flat >> 6, nn = flat & 63;
        lds[c][nn] = src[(size_t)c * N_ + nn];
    }
    __syncthreads();
    if (threadIdx.x < 64) {
        float ss = 0.f;
        #pragma unroll 8
        for (int c = 0; c < C_; ++c) { float v = lds[c][threadIdx.x]; ss += v * v; }
        nrm[threadIdx.x] = sqrtf(ss) + EPS_;
    }
    __syncthreads();
    float* dstf = xnt + ((size_t)b * N_ + n0) * C_;
    __hip_bfloat16* dstb = xnb + ((size_t)b * N_ + n0) * C_;
    #pragma unroll 4
    for (int i = 0; i < 32; ++i) {
        int flat = i * TPB + threadIdx.x;
        int nn = flat >> 7, c = flat & 127;
        float v = lds[c][nn] / nrm[nn];
        dstf[(size_t)nn * C_ + c] = v;
        dstb[(size_t)nn * C_ + c] = __float2bfloat16(v);
    }
}

// ---------------------------------------------------------------------------
// 2) xtb[b][n][c] = bf16(x[b][c][n])   (raw features for conv gather)
// ---------------------------------------------------------------------------
__global__ __launch_bounds__(TPB) void transpose_bf16_kernel(const float* __restrict__ x,
                                                             __hip_bfloat16* __restrict__ xtb) {
    __shared__ float lds[128][65];
    int b = blockIdx.x >> 4, n0 = (blockIdx.x & 15) << 6;
    const float* src = x + (size_t)b * CN_ + n0;
    #pragma unroll 4
    for (int i = 0; i < 32; ++i) {
        int flat = i * TPB + threadIdx.x;
        int c = flat >> 6, nn = flat & 63;
        lds[c][nn] = src[(size_t)c * N_ + nn];
    }
    __syncthreads();
    __hip_bfloat16* dst = xtb + (size_t)b * CN_ + (size_t)n0 * C_;
    #pragma unroll 4
    for (int i = 0; i < 32; ++i) {
        int flat = i * TPB + threadIdx.x;
        int nn = flat >> 7, c = flat & 127;
        dst[(size_t)nn * C_ + c] = __float2bfloat16(lds[c][nn]);
    }
}

// ---------------------------------------------------------------------------
// 3) split-bf16 weights: wh/wl [k][o][c]
// ---------------------------------------------------------------------------
__global__ __launch_bounds__(TPB) void wbprep_kernel(const float* __restrict__ W,
                                                     __hip_bfloat16* __restrict__ wh,
                                                     __hip_bfloat16* __restrict__ wl) {
    int t = blockIdx.x * TPB + threadIdx.x;
    int k = t / (C_ * C_);
    int r = t - k * (C_ * C_);
    int o = r >> 7, c = r & 127;
    float w = W[((size_t)o * C_ + c) * K_ + k];
    __hip_bfloat16 h = __float2bfloat16(w);
    wh[t] = h;
    wl[t] = __float2bfloat16(w - __bfloat162float(h));
}

// ---------------------------------------------------------------------------
// 4) phase-1: bf16 MFMA sim + approx top-16 per row via packed u32 keyset.
//    512 threads: (row = tid&127, 32-col seg = tid>>7); warm keyset across
//    all 8 col-tiles; one key-based merge at the end.
// ---------------------------------------------------------------------------
__global__ __launch_bounds__(STPB, 1) void sim_mfma_topk_kernel(const __hip_bfloat16* __restrict__ xnb,
                                                                int* __restrict__ ci) {
    __shared__ __align__(16) __hip_bfloat16 Ab[2][128 * 64];   // rows, 2 c-halves, swizzled
    __shared__ __align__(16) __hip_bfloat16 Bb[2][128 * 64];   // cols, 2 c-halves, swizzled
    __shared__ __align__(16) float scanb[128 * 132];           // sim tile [128][132]; key buf aliases

    const int tid = threadIdx.x;
    const int lane = tid & 63;
    const int wv = tid >> 6;                     // 0..7
    const int b  = blockIdx.x >> 3;
    const int n0 = (blockIdx.x & 7) << 7;
    const __hip_bfloat16* xb = xnb + (size_t)b * CN_;
    const int l15 = lane & 15, l7 = lane & 7, lq = lane >> 4;
    const int swz = ((lane & 7) ^ (lane >> 3)) * 8;
    const int srow = tid & 127;                  // owned row
    const int sseg = tid >> 7;                   // owned 32-col segment
    const int grow = n0 + srow;

// stage 128 tokens' 64c half HH from token base TB into linear dst (pre-swizzled src)
#define STAGE_HALF(DST, TB, HH)                                            \
    {                                                                      \
        _Pragma("unroll")                                                  \
        for (int p_ = 0; p_ < 2; ++p_) {                                   \
            int r0_ = 16 * wv + 8 * p_;                                    \
            int tok_ = (TB) + r0_ + (lane >> 3);                           \
            gload_lds16(xb + (size_t)tok_ * C_ + (HH) * 64 + swz,          \
                        (DST) + r0_ * 64);                                 \
        }                                                                  \
    }

    STAGE_HALF(&Ab[0][0], n0, 0)
    STAGE_HALF(&Ab[1][0], n0, 1)
    STAGE_HALF(&Bb[0][0], 0, 0)
    STAGE_HALF(&Bb[1][0], 0, 1)
    __syncthreads();                             // A + B(0) ready

    // A-fragments: constant across all m-tiles (wave owns rows 16wv..16wv+15)
    s16x8 af[2][2];
    #pragma unroll
    for (int h = 0; h < 2; ++h)
        #pragma unroll
        for (int kc = 0; kc < 2; ++kc)
            af[h][kc] = *(const s16x8*)&Ab[h][(16 * wv + l15) * 64 + (((kc * 4 + lq) ^ l7) << 3)];

    unsigned keys[16];                           // warm unsorted top-16 keyset
    #pragma unroll
    for (int p = 0; p < 16; ++p) keys[p] = (unsigned)p;   // distinct, below any real key
    unsigned thr = 0u;

    #pragma unroll 1
    for (int mt = 0; mt < 8; ++mt) {
        const int m0 = mt << 7;
        f32x4 acc[8];
        #pragma unroll
        for (int nt = 0; nt < 8; ++nt) acc[nt] = (f32x4){0.f, 0.f, 0.f, 0.f};

        #pragma unroll
        for (int h = 0; h < 2; ++h)
            #pragma unroll
            for (int kc = 0; kc < 2; ++kc) {
                const int phys = ((kc * 4 + lq) ^ l7) << 3;
                #pragma unroll
                for (int nt = 0; nt < 8; ++nt) {
                    s16x8 bb = *(const s16x8*)&Bb[h][(16 * nt + l15) * 64 + phys];
                    acc[nt] = __builtin_amdgcn_mfma_f32_16x16x32_bf16(af[h][kc], bb, acc[nt], 0, 0, 0);
                }
            }
        __syncthreads();                         // MFMA reads of Bb done; prev scan done

        if (mt < 7) {                            // overwrite Bb with next col-tile
            STAGE_HALF(&Bb[0][0], m0 + 128, 0)
            STAGE_HALF(&Bb[1][0], m0 + 128, 1)
        }
        // dump sims: C layout col=lane&15 (B-row=m), row=(lane>>4)*4+r (A-row=n)
        #pragma unroll
        for (int nt = 0; nt < 8; ++nt)
            #pragma unroll
            for (int r = 0; r < 4; ++r)
                scanb[(16 * wv + 4 * lq + r) * 132 + 16 * nt + l15] = acc[nt][r];
        __syncthreads();                         // dump visible; gll drained (next Bb ready)

        // scan own (row, 32-col segment), all 512 threads, key-based
        const float* sp = &scanb[srow * 132 + (sseg << 5)];
        const int cb = m0 + (sseg << 5);
        const unsigned gb = 1023u - (unsigned)cb;   // key low-field base
        const int drel = grow - cb;                 // 0..31 if self in this segment
        #pragma unroll 1
        for (int q = 0; q < 8; ++q) {
            float4 v4 = *(const float4*)(sp + 4 * q);
            float vv[4] = {v4.x, v4.y, v4.z, v4.w};
            #pragma unroll
            for (int j = 0; j < 4; ++j) {
                float v = (4 * q + j == drel) ? INFV : vv[j];   // self always wins
                KINSERT(keys, thr, simkey(v, gb - (unsigned)(4 * q + j)))
            }
        }
    }

    // final: segs 1..3 dump keysets; seg-0 thread merges 48 keys
    __syncthreads();                             // last scan done; scanb reusable
    unsigned* fk = (unsigned*)scanb;             // [128][3][16] u32
    if (sseg) {
        int base = (srow * 3 + (sseg - 1)) * 16;
        #pragma unroll
        for (int p = 0; p < 16; ++p)
            fk[base + ((p + srow) & 15)] = keys[p];   // bank-rotated
    }
    __syncthreads();
    if (tid < 128) {                             // sseg==0, srow==tid
        #pragma unroll 1
        for (int g = 0; g < 3; ++g)
            #pragma unroll
            for (int p = 0; p < 16; ++p) {
                unsigned k = fk[(tid * 3 + g) * 16 + ((p + tid) & 15)];
                KINSERT(keys, thr, k)
            }
        int* op = ci + ((size_t)b * N_ + grow) * 16;
        #pragma unroll
        for (int p = 0; p < 16; ++p) op[p] = 1023 - (int)(keys[p] & 1023u);
    }
#undef STAGE_HALF
}

// ---------------------------------------------------------------------------
// 5) rescore: exact fp32 dots of the 16 candidates -> stable top-9 indices
// ---------------------------------------------------------------------------
__global__ __launch_bounds__(TPB) void rescore_kernel(const float* __restrict__ xnt,
                                                      const int* __restrict__ ci,
                                                      int* __restrict__ idxo) {
    const int tid = threadIdx.x;
    const int g = tid >> 4, l = tid & 15;
    const size_t row = (size_t)blockIdx.x * 16 + g;       // global row 0..32767
    const int nrow = (int)(row & (N_ - 1));               // token index within batch
    const float* xbase = xnt + (row >> 10) * (size_t)CN_; // batch base
    const float* rvp = xbase + (size_t)nrow * C_;

    float rv[8];
    #pragma unroll
    for (int t = 0; t < 8; ++t) rv[t] = rvp[t * 16 + l];

    float val[9]; int id[9];
    #pragma unroll
    for (int p = 0; p < 9; ++p) { val[p] = -1e30f; id[p] = -1; }

    const int* cp = ci + row * 16;
    #pragma unroll 1
    for (int j = 0; j < 16; ++j) {
        int cand = cp[j];
        const float* cv = xbase + (size_t)cand * C_;
        float s = 0.f;
        #pragma unroll
        for (int t = 0; t < 8; ++t) s = fmaf(rv[t], cv[t * 16 + l], s);
        #pragma unroll
        for (int d = 1; d < 16; d <<= 1) s += __shfl_xor(s, d);
        float v = (cand == nrow) ? INFV : s;
        INSERT9(val, id, v, cand)
    }
    if (l == 0) {
        int* op = idxo + row * 9;
        #pragma unroll
        for (int p = 0; p < 9; ++p) op[p] = id[p];
    }
}

// ---------------------------------------------------------------------------
// 6) MFMA conv (unchanged, passing): 128o x 128n per block
// ---------------------------------------------------------------------------
__global__ __launch_bounds__(TPB) void conv_mfma_kernel(const __hip_bfloat16* __restrict__ xtb,
                                                        const __hip_bfloat16* __restrict__ wbh,
                                                        const __hip_bfloat16* __restrict__ wbl,
                                                        const int* __restrict__ idxi,
                                                        float* __restrict__ out) {
    __shared__ __align__(16) __hip_bfloat16 gbuf[2][128 * 64];
    __shared__ __align__(16) __hip_bfloat16 hbuf[2][128 * 64];
    __shared__ __align__(16) __hip_bfloat16 lbuf[2][128 * 64];
    __shared__ int ids[K_ * 128];

    const int tid = threadIdx.x;
    const int lane = tid & 63;
    const int wv = tid >> 6;
    const int b  = blockIdx.x >> 3;
    const int n0 = (blockIdx.x & 7) << 7;
    const __hip_bfloat16* xb = xtb + (size_t)b * CN_;

    for (int j = tid; j < K_ * 128; j += TPB) {
        int k = j >> 7, r = j & 127;
        ids[j] = idxi[((size_t)b * N_ + n0 + r) * K_ + k];
    }
    __syncthreads();

    f32x4 acc[2][8];
    #pragma unroll
    for (int mt = 0; mt < 2; ++mt)
        #pragma unroll
        for (int nt = 0; nt < 8; ++nt) acc[mt][nt] = (f32x4){0.f, 0.f, 0.f, 0.f};

    const int swz = ((lane & 7) ^ (lane >> 3)) * 8;

#define CONV_STAGE(S, PB)                                                               \
    {                                                                                   \
        const int k_ = (S) >> 1, ch_ = ((S) & 1) * 64;                                  \
        _Pragma("unroll")                                                               \
        for (int q_ = 0; q_ < 4; ++q_) {                                                \
            int row_ = 32 * wv + 8 * q_ + (lane >> 3);                                  \
            int tok_ = ids[k_ * 128 + row_];                                            \
            gload_lds16(xb + (size_t)tok_ * C_ + ch_ + swz, &gbuf[PB][(32 * wv + 8 * q_) * 64]); \
            const size_t wr_ = ((size_t)k_ * 128 + row_) * C_ + ch_ + swz;              \
            gload_lds16(wbh + wr_, &hbuf[PB][(32 * wv + 8 * q_) * 64]);                 \
            gload_lds16(wbl + wr_, &lbuf[PB][(32 * wv + 8 * q_) * 64]);                 \
        }                                                                               \
    }

    CONV_STAGE(0, 0)
    __syncthreads();

    const int l15 = lane & 15, l7 = lane & 7, lq = lane >> 4;
    int pb = 0;
    #pragma unroll 1
    for (int s = 0; s < 18; ++s) {
        if (s < 17) CONV_STAGE(s + 1, pb ^ 1)
        const __hip_bfloat16* G = gbuf[pb];
        const __hip_bfloat16* H = hbuf[pb];
        const __hip_bfloat16* L = lbuf[pb];
        #pragma unroll
        for (int kc = 0; kc < 2; ++kc) {
            const int phys = ((kc * 4 + lq) ^ l7) * 8;
            s16x8 bb[8];
            #pragma unroll
            for (int nt = 0; nt < 8; ++nt)
                bb[nt] = *(const s16x8*)&G[(16 * nt + l15) * 64 + phys];
            #pragma unroll
            for (int mt = 0; mt < 2; ++mt) {
                const int orow = (32 * wv + 16 * mt + l15) * 64 + phys;
                s16x8 ah = *(const s16x8*)&H[orow];
                s16x8 al = *(const s16x8*)&L[orow];
                #pragma unroll
                for (int nt = 0; nt < 8; ++nt) {
                    acc[mt][nt] = __builtin_amdgcn_mfma_f32_16x16x32_bf16(ah, bb[nt], acc[mt][nt], 0, 0, 0);
                    acc[mt][nt] = __builtin_amdgcn_mfma_f32_16x16x32_bf16(al, bb[nt], acc[mt][nt], 0, 0, 0);
                }
            }
        }
        __syncthreads();
        pb ^= 1;
    }

    float* ob = out + (size_t)b * CN_;
    #pragma unroll
    for (int mt = 0; mt < 2; ++mt)
        #pragma unroll
        for (int nt = 0; nt < 8; ++nt) {
            int o = 32 * wv + 16 * mt + lq * 4;
            int n = n0 + 16 * nt + l15;
            #pragma unroll
            for (int r = 0; r < 4; ++r)
                ob[(size_t)(o + r) * N_ + n] = acc[mt][nt][r];
        }
#undef CONV_STAGE
}

// ---------------------------------------------------------------------------
extern "C" void kernel_launch(void* const* d_in, const int* in_sizes, int n_in,
                              void* d_out, int out_size, void* d_ws, size_t ws_size,
                              hipStream_t stream) {
    (void)in_sizes; (void)n_in; (void)out_size; (void)ws_size;
    const float* x = (const float*)d_in[0];
    const float* W = (const float*)d_in[1];
    float* out = (float*)d_out;
    float* ws  = (float*)d_ws;

    float* xnt = ws + XNT_OFF;
    __hip_bfloat16* xnb = (__hip_bfloat16*)(ws + XNB_OFF);
    __hip_bfloat16* xtb = (__hip_bfloat16*)(ws + XNB_OFF);  // aliases xnb (disjoint lifetime)
    __hip_bfloat16* wbh = (__hip_bfloat16*)(ws + WBH_OFF);
    __hip_bfloat16* wbl = (__hip_bfloat16*)(ws + WBL_OFF);
    int* ci  = (int*)(ws + CI_OFF);
    int* idx = (int*)(ws + IDX_OFF);

    normtrans_kernel<<<B_ * 16, TPB, 0, stream>>>(x, xnt, xnb);
    wbprep_kernel<<<(K_ * C_ * C_) / TPB, TPB, 0, stream>>>(W, wbh, wbl);
    sim_mfma_topk_kernel<<<B_ * 8, STPB, 0, stream>>>(xnb, ci);
    rescore_kernel<<<(B_ * N_) / 16, TPB, 0, stream>>>(xnt, ci, idx);
    transpose_bf16_kernel<<<B_ * 16, TPB, 0, stream>>>(x, xtb);  // xnb dead now
    conv_mfma_kernel<<<B_ * 8, TPB, 0, stream>>>(xtb, wbh, wbl, idx, out);
}

// Round 12
// 157.725 us; speedup vs baseline: 4.6757x; 1.0228x over previous
//
#include <hip/hip_runtime.h>
#include <hip/hip_bf16.h>

#define TPB 256
#define STPB 512

typedef float f32x4 __attribute__((ext_vector_type(4)));
typedef short s16x8 __attribute__((ext_vector_type(8)));

static constexpr int B_ = 32;
static constexpr int C_ = 128;
static constexpr int N_ = 1024;
static constexpr int K_ = 9;
static constexpr int CN_ = C_ * N_;
static constexpr float INFV = 1.0e10f;
static constexpr float EPS_ = 1e-8f;

// ws layout (float slots)
static constexpr size_t XNT_OFF = 0;                             // xnt [B][N][C] fp32
static constexpr size_t XNB_OFF = (size_t)B_ * CN_;              // xnb [B][N][C] bf16 (xtb aliases later)
static constexpr size_t WBH_OFF = XNB_OFF + (size_t)B_ * CN_ / 2;
static constexpr size_t WBL_OFF = WBH_OFF + (size_t)K_ * C_ * C_ / 2;
static constexpr size_t CI_OFF  = WBL_OFF + (size_t)K_ * C_ * C_ / 2;  // [B][N][16] int
static constexpr size_t IDX_OFF = CI_OFF + (size_t)B_ * N_ * 16;       // [B][N][9] int

__device__ __forceinline__ void gload_lds16(const void* g, void* l) {
    __builtin_amdgcn_global_load_lds((const __attribute__((address_space(1))) void*)g,
                                     (__attribute__((address_space(3))) void*)l, 16, 0, 0);
}

// exact stable top-9 insert (rescore only)
#define INSERT9(Vv, Ii, vexpr, gmexpr)                                      \
    {                                                                       \
        float _v = (vexpr); int _gm = (gmexpr);                             \
        bool bp[9];                                                         \
        _Pragma("unroll")                                                   \
        for (int _p = 0; _p < 9; ++_p)                                      \
            bp[_p] = (_v > Vv[_p]) || (_v == Vv[_p] && _gm < Ii[_p]);       \
        if (bp[8]) {                                                        \
            _Pragma("unroll")                                               \
            for (int _p = 8; _p >= 1; --_p) {                               \
                Vv[_p] = bp[_p - 1] ? Vv[_p - 1] : (bp[_p] ? _v  : Vv[_p]); \
                Ii[_p] = bp[_p - 1] ? Ii[_p - 1] : (bp[_p] ? _gm : Ii[_p]); \
            }                                                               \
            if (bp[0]) { Vv[0] = _v; Ii[0] = _gm; }                         \
        }                                                                   \
    }

// unsorted top-16 keyset insert: replace unique min slot, recompute min tree
#define KINSERT(KEYS, THR, KEXPR)                                           \
    {                                                                       \
        unsigned _k = (KEXPR);                                              \
        if (_k > (THR)) {                                                   \
            _Pragma("unroll")                                               \
            for (int _p = 0; _p < 16; ++_p)                                 \
                KEYS[_p] = (KEYS[_p] == (THR)) ? _k : KEYS[_p];             \
            unsigned _a0 = min(KEYS[0],  KEYS[1]);                          \
            unsigned _a1 = min(KEYS[2],  KEYS[3]);                          \
            unsigned _a2 = min(KEYS[4],  KEYS[5]);                          \
            unsigned _a3 = min(KEYS[6],  KEYS[7]);                          \
            unsigned _a4 = min(KEYS[8],  KEYS[9]);                          \
            unsigned _a5 = min(KEYS[10], KEYS[11]);                         \
            unsigned _a6 = min(KEYS[12], KEYS[13]);                         \
            unsigned _a7 = min(KEYS[14], KEYS[15]);                         \
            _a0 = min(_a0, _a1); _a2 = min(_a2, _a3);                       \
            _a4 = min(_a4, _a5); _a6 = min(_a6, _a7);                       \
            _a0 = min(_a0, _a2); _a4 = min(_a4, _a6);                       \
            (THR) = min(_a0, _a4);                                          \
        }                                                                   \
    }

// monotone (value, smaller-index-wins) packed key; drops 10 low mantissa bits
__device__ __forceinline__ unsigned simkey(float v, unsigned lowfield) {
    unsigned u = __float_as_uint(v);
    u ^= ((unsigned)((int)u >> 31) | 0x80000000u);
    return (u & 0xFFFFFC00u) | lowfield;
}

// ---------------------------------------------------------------------------
// 1) normtrans: xnt[b][n][c] = x[b][c][n]/(||x[:,n]||+eps) fp32; xnb = bf16(same)
// ---------------------------------------------------------------------------
__global__ __launch_bounds__(TPB) void normtrans_kernel(const float* __restrict__ x,
                                                        float* __restrict__ xnt,
                                                        __hip_bfloat16* __restrict__ xnb) {
    __shared__ float lds[128][65];
    __shared__ float nrm[64];
    int b = blockIdx.x >> 4, n0 = (blockIdx.x & 15) << 6;
    const float* src = x + (size_t)b * CN_ + n0;
    #pragma unroll 4
    for (int i = 0; i < 32; ++i) {
        int flat = i * TPB + threadIdx.x;
        int c = flat >> 6, nn = flat & 63;
        lds[c][nn] = src[(size_t)c * N_ + nn];
    }
    __syncthreads();
    if (threadIdx.x < 64) {
        float ss = 0.f;
        #pragma unroll 8
        for (int c = 0; c < C_; ++c) { float v = lds[c][threadIdx.x]; ss += v * v; }
        nrm[threadIdx.x] = sqrtf(ss) + EPS_;
    }
    __syncthreads();
    float* dstf = xnt + ((size_t)b * N_ + n0) * C_;
    __hip_bfloat16* dstb = xnb + ((size_t)b * N_ + n0) * C_;
    #pragma unroll 4
    for (int i = 0; i < 32; ++i) {
        int flat = i * TPB + threadIdx.x;
        int nn = flat >> 7, c = flat & 127;
        float v = lds[c][nn] / nrm[nn];
        dstf[(size_t)nn * C_ + c] = v;
        dstb[(size_t)nn * C_ + c] = __float2bfloat16(v);
    }
}

// ---------------------------------------------------------------------------
// 2) xtb[b][n][c] = bf16(x[b][c][n])   (raw features for conv gather)
// ---------------------------------------------------------------------------
__global__ __launch_bounds__(TPB) void transpose_bf16_kernel(const float* __restrict__ x,
                                                             __hip_bfloat16* __restrict__ xtb) {
    __shared__ float lds[128][65];
    int b = blockIdx.x >> 4, n0 = (blockIdx.x & 15) << 6;
    const float* src = x + (size_t)b * CN_ + n0;
    #pragma unroll 4
    for (int i = 0; i < 32; ++i) {
        int flat = i * TPB + threadIdx.x;
        int c = flat >> 6, nn = flat & 63;
        lds[c][nn] = src[(size_t)c * N_ + nn];
    }
    __syncthreads();
    __hip_bfloat16* dst = xtb + (size_t)b * CN_ + (size_t)n0 * C_;
    #pragma unroll 4
    for (int i = 0; i < 32; ++i) {
        int flat = i * TPB + threadIdx.x;
        int nn = flat >> 7, c = flat & 127;
        dst[(size_t)nn * C_ + c] = __float2bfloat16(lds[c][nn]);
    }
}

// ---------------------------------------------------------------------------
// 3) split-bf16 weights: wh/wl [k][o][c]
// ---------------------------------------------------------------------------
__global__ __launch_bounds__(TPB) void wbprep_kernel(const float* __restrict__ W,
                                                     __hip_bfloat16* __restrict__ wh,
                                                     __hip_bfloat16* __restrict__ wl) {
    int t = blockIdx.x * TPB + threadIdx.x;
    int k = t / (C_ * C_);
    int r = t - k * (C_ * C_);
    int o = r >> 7, c = r & 127;
    float w = W[((size_t)o * C_ + c) * K_ + k];
    __hip_bfloat16 h = __float2bfloat16(w);
    wh[t] = h;
    wl[t] = __float2bfloat16(w - __bfloat162float(h));
}

// ---------------------------------------------------------------------------
// 4) phase-1: swapped-operand MFMA sim; lane-local rows -> register-direct
//    keyset scan (no LDS dump/scan). Block = (b, 64-row tile); 8 waves:
//    wave = (rowblock rb = wv&3, col-half ch = wv>>2). Grid 512, 2 blocks/CU.
// ---------------------------------------------------------------------------
__global__ __launch_bounds__(STPB, 2) void sim_mfma_topk_kernel(const __hip_bfloat16* __restrict__ xnb,
                                                                int* __restrict__ ci) {
    __shared__ __align__(16) ushort SH[8192 + 16384];   // Ab [2][64*64] | Bb [2][128*64]
    ushort* Ab = SH;                                    // mbuf (u32[1024]) aliases Ab at merge
    ushort* Bb = SH + 8192;

    const int tid = threadIdx.x;
    const int lane = tid & 63;
    const int wv = tid >> 6;                  // 0..7
    const int rb = wv & 3;                    // 16-row block within the 64-row tile
    const int ch = wv >> 2;                   // col half (64 cols of each 128-tile)
    const int b  = blockIdx.x >> 4;
    const int n0 = (blockIdx.x & 15) << 6;    // 64 rows per block
    const __hip_bfloat16* xb = xnb + (size_t)b * CN_;
    const int l15 = lane & 15, l7 = lane & 7, lq = lane >> 4;
    const int swz = ((lane & 7) ^ (lane >> 3)) * 8;
    const int grow = n0 + 16 * rb + l15;      // the row this lane selects for

    // stage Ab (64 rows x 128c, 2 halves): 16 gll units, 2 per wave
    #pragma unroll
    for (int q = 0; q < 2; ++q) {
        int u = 2 * wv + q;
        int hh = u >> 3, r0 = (u & 7) * 8;
        gload_lds16(xb + (size_t)(n0 + r0 + (lane >> 3)) * C_ + hh * 64 + swz,
                    Ab + hh * 4096 + r0 * 64);
    }
    // stage Bb tile 0 (tokens 0..127): 32 units, 4 per wave
    #pragma unroll
    for (int q = 0; q < 4; ++q) {
        int u = 4 * wv + q;
        int hh = u >> 4, r0 = (u & 15) * 8;
        gload_lds16(xb + (size_t)(r0 + (lane >> 3)) * C_ + hh * 64 + swz,
                    Bb + hh * 8192 + r0 * 64);
    }
    __syncthreads();

    // row fragments (B-operand after swap), constant across all mt
    s16x8 af[2][2];
    #pragma unroll
    for (int h = 0; h < 2; ++h)
        #pragma unroll
        for (int kc = 0; kc < 2; ++kc)
            af[h][kc] = *(const s16x8*)&Ab[h * 4096 + (16 * rb + l15) * 64 + (((kc * 4 + lq) ^ l7) << 3)];

    unsigned keys[16];
    #pragma unroll
    for (int p = 0; p < 16; ++p) keys[p] = (unsigned)p;   // distinct, below any real key
    unsigned thr = 0u;

    #pragma unroll 1
    for (int mt = 0; mt < 8; ++mt) {
        f32x4 acc[4];
        #pragma unroll
        for (int t = 0; t < 4; ++t) acc[t] = (f32x4){0.f, 0.f, 0.f, 0.f};

        #pragma unroll
        for (int h = 0; h < 2; ++h)
            #pragma unroll
            for (int kc = 0; kc < 2; ++kc) {
                const int phys = ((kc * 4 + lq) ^ l7) << 3;
                #pragma unroll
                for (int t = 0; t < 4; ++t) {
                    s16x8 bb = *(const s16x8*)&Bb[h * 8192 + (64 * ch + 16 * t + l15) * 64 + phys];
                    // SWAPPED operands: A = col fragment, B = row fragment
                    acc[t] = __builtin_amdgcn_mfma_f32_16x16x32_bf16(bb, af[h][kc], acc[t], 0, 0, 0);
                }
            }
        __syncthreads();                      // all MFMA reads of Bb done

        if (mt < 7) {                         // stage next 128 tokens
            #pragma unroll
            for (int q = 0; q < 4; ++q) {
                int u = 4 * wv + q;
                int hh = u >> 4, r0 = (u & 15) * 8;
                gload_lds16(xb + (size_t)(128 * (mt + 1) + r0 + (lane >> 3)) * C_ + hh * 64 + swz,
                            Bb + hh * 8192 + r0 * 64);
            }
        }

        // register-direct scan: lane owns row grow; cols = m0+64ch+16t+4lq+r
        const int colb = (mt << 7) + 64 * ch + 4 * lq;
        #pragma unroll
        for (int t = 0; t < 4; ++t)
            #pragma unroll
            for (int r = 0; r < 4; ++r) {
                int gcol = colb + 16 * t + r;
                float v = acc[t][r];
                if (gcol == grow) v = INFV;   // self always a candidate
                KINSERT(keys, thr, simkey(v, 1023u - (unsigned)gcol))
            }
        __syncthreads();                      // drains gll: next Bb ready
    }

    // merge the 4 lq lanes of each (row, col-half): butterfly over lane^16, ^32.
    // SNAPSHOT the partner's full keyset BEFORE inserting (in-place shfl merge
    // is a read-during-mutation hazard -> duplicate keys -> set corruption).
    // Partner col-sets are disjoint at both steps, so no duplicates possible.
    #pragma unroll
    for (int d = 16; d <= 32; d <<= 1) {
        unsigned inc[16];
        #pragma unroll
        for (int p = 0; p < 16; ++p)
            inc[p] = (unsigned)__shfl_xor((int)keys[p], d);
        #pragma unroll
        for (int p = 0; p < 16; ++p) KINSERT(keys, thr, inc[p])
    }

    // cross-wave merge (col half 1 -> half 0) via small LDS buffer over Ab
    unsigned* mbuf = (unsigned*)SH;           // [64 rows][16 keys]
    if (ch == 1 && lq == 0) {
        #pragma unroll
        for (int p = 0; p < 16; ++p) mbuf[(16 * rb + l15) * 16 + p] = keys[p];
    }
    __syncthreads();
    if (ch == 0 && lq == 0) {
        #pragma unroll
        for (int p = 0; p < 16; ++p) KINSERT(keys, thr, mbuf[(16 * rb + l15) * 16 + p])
        int* op = ci + ((size_t)b * N_ + grow) * 16;
        #pragma unroll
        for (int p = 0; p < 16; ++p) op[p] = 1023 - (int)(keys[p] & 1023u);
    }
}

// ---------------------------------------------------------------------------
// 5) rescore: exact fp32 dots of the 16 candidates -> stable top-9 indices
// ---------------------------------------------------------------------------
__global__ __launch_bounds__(TPB) void rescore_kernel(const float* __restrict__ xnt,
                                                      const int* __restrict__ ci,
                                                      int* __restrict__ idxo) {
    const int tid = threadIdx.x;
    const int g = tid >> 4, l = tid & 15;
    const size_t row = (size_t)blockIdx.x * 16 + g;       // global row 0..32767
    const int nrow = (int)(row & (N_ - 1));               // token index within batch
    const float* xbase = xnt + (row >> 10) * (size_t)CN_; // batch base
    const float* rvp = xbase + (size_t)nrow * C_;

    float rv[8];
    #pragma unroll
    for (int t = 0; t < 8; ++t) rv[t] = rvp[t * 16 + l];

    float val[9]; int id[9];
    #pragma unroll
    for (int p = 0; p < 9; ++p) { val[p] = -1e30f; id[p] = -1; }

    const int* cp = ci + row * 16;
    #pragma unroll 4
    for (int j = 0; j < 16; ++j) {
        int cand = cp[j];
        const float* cv = xbase + (size_t)cand * C_;
        float s = 0.f;
        #pragma unroll
        for (int t = 0; t < 8; ++t) s = fmaf(rv[t], cv[t * 16 + l], s);
        #pragma unroll
        for (int d = 1; d < 16; d <<= 1) s += __shfl_xor(s, d);
        float v = (cand == nrow) ? INFV : s;
        INSERT9(val, id, v, cand)
    }
    if (l == 0) {
        int* op = idxo + row * 9;
        #pragma unroll
        for (int p = 0; p < 9; ++p) op[p] = id[p];
    }
}

// ---------------------------------------------------------------------------
// 6) MFMA conv (unchanged, passing): 128o x 128n per block
// ---------------------------------------------------------------------------
__global__ __launch_bounds__(TPB) void conv_mfma_kernel(const __hip_bfloat16* __restrict__ xtb,
                                                        const __hip_bfloat16* __restrict__ wbh,
                                                        const __hip_bfloat16* __restrict__ wbl,
                                                        const int* __restrict__ idxi,
                                                        float* __restrict__ out) {
    __shared__ __align__(16) __hip_bfloat16 gbuf[2][128 * 64];
    __shared__ __align__(16) __hip_bfloat16 hbuf[2][128 * 64];
    __shared__ __align__(16) __hip_bfloat16 lbuf[2][128 * 64];
    __shared__ int ids[K_ * 128];

    const int tid = threadIdx.x;
    const int lane = tid & 63;
    const int wv = tid >> 6;
    const int b  = blockIdx.x >> 3;
    const int n0 = (blockIdx.x & 7) << 7;
    const __hip_bfloat16* xb = xtb + (size_t)b * CN_;

    for (int j = tid; j < K_ * 128; j += TPB) {
        int k = j >> 7, r = j & 127;
        ids[j] = idxi[((size_t)b * N_ + n0 + r) * K_ + k];
    }
    __syncthreads();

    f32x4 acc[2][8];
    #pragma unroll
    for (int mt = 0; mt < 2; ++mt)
        #pragma unroll
        for (int nt = 0; nt < 8; ++nt) acc[mt][nt] = (f32x4){0.f, 0.f, 0.f, 0.f};

    const int swz = ((lane & 7) ^ (lane >> 3)) * 8;

#define CONV_STAGE(S, PB)                                                               \
    {                                                                                   \
        const int k_ = (S) >> 1, ch_ = ((S) & 1) * 64;                                  \
        _Pragma("unroll")                                                               \
        for (int q_ = 0; q_ < 4; ++q_) {                                                \
            int row_ = 32 * wv + 8 * q_ + (lane >> 3);                                  \
            int tok_ = ids[k_ * 128 + row_];                                            \
            gload_lds16(xb + (size_t)tok_ * C_ + ch_ + swz, &gbuf[PB][(32 * wv + 8 * q_) * 64]); \
            const size_t wr_ = ((size_t)k_ * 128 + row_) * C_ + ch_ + swz;              \
            gload_lds16(wbh + wr_, &hbuf[PB][(32 * wv + 8 * q_) * 64]);                 \
            gload_lds16(wbl + wr_, &lbuf[PB][(32 * wv + 8 * q_) * 64]);                 \
        }                                                                               \
    }

    CONV_STAGE(0, 0)
    __syncthreads();

    const int l15 = lane & 15, l7 = lane & 7, lq = lane >> 4;
    int pb = 0;
    #pragma unroll 1
    for (int s = 0; s < 18; ++s) {
        if (s < 17) CONV_STAGE(s + 1, pb ^ 1)
        const __hip_bfloat16* G = gbuf[pb];
        const __hip_bfloat16* H = hbuf[pb];
        const __hip_bfloat16* L = lbuf[pb];
        #pragma unroll
        for (int kc = 0; kc < 2; ++kc) {
            const int phys = ((kc * 4 + lq) ^ l7) * 8;
            s16x8 bb[8];
            #pragma unroll
            for (int nt = 0; nt < 8; ++nt)
                bb[nt] = *(const s16x8*)&G[(16 * nt + l15) * 64 + phys];
            #pragma unroll
            for (int mt = 0; mt < 2; ++mt) {
                const int orow = (32 * wv + 16 * mt + l15) * 64 + phys;
                s16x8 ah = *(const s16x8*)&H[orow];
                s16x8 al = *(const s16x8*)&L[orow];
                #pragma unroll
                for (int nt = 0; nt < 8; ++nt) {
                    acc[mt][nt] = __builtin_amdgcn_mfma_f32_16x16x32_bf16(ah, bb[nt], acc[mt][nt], 0, 0, 0);
                    acc[mt][nt] = __builtin_amdgcn_mfma_f32_16x16x32_bf16(al, bb[nt], acc[mt][nt], 0, 0, 0);
                }
            }
        }
        __syncthreads();
        pb ^= 1;
    }

    float* ob = out + (size_t)b * CN_;
    #pragma unroll
    for (int mt = 0; mt < 2; ++mt)
        #pragma unroll
        for (int nt = 0; nt < 8; ++nt) {
            int o = 32 * wv + 16 * mt + lq * 4;
            int n = n0 + 16 * nt + l15;
            #pragma unroll
            for (int r = 0; r < 4; ++r)
                ob[(size_t)(o + r) * N_ + n] = acc[mt][nt][r];
        }
#undef CONV_STAGE
}

// ---------------------------------------------------------------------------
extern "C" void kernel_launch(void* const* d_in, const int* in_sizes, int n_in,
                              void* d_out, int out_size, void* d_ws, size_t ws_size,
                              hipStream_t stream) {
    (void)in_sizes; (void)n_in; (void)out_size; (void)ws_size;
    const float* x = (const float*)d_in[0];
    const float* W = (const float*)d_in[1];
    float* out = (float*)d_out;
    float* ws  = (float*)d_ws;

    float* xnt = ws + XNT_OFF;
    __hip_bfloat16* xnb = (__hip_bfloat16*)(ws + XNB_OFF);
    __hip_bfloat16* xtb = (__hip_bfloat16*)(ws + XNB_OFF);  // aliases xnb (disjoint lifetime)
    __hip_bfloat16* wbh = (__hip_bfloat16*)(ws + WBH_OFF);
    __hip_bfloat16* wbl = (__hip_bfloat16*)(ws + WBL_OFF);
    int* ci  = (int*)(ws + CI_OFF);
    int* idx = (int*)(ws + IDX_OFF);

    normtrans_kernel<<<B_ * 16, TPB, 0, stream>>>(x, xnt, xnb);
    wbprep_kernel<<<(K_ * C_ * C_) / TPB, TPB, 0, stream>>>(W, wbh, wbl);
    sim_mfma_topk_kernel<<<B_ * 16, STPB, 0, stream>>>(xnb, ci);
    rescore_kernel<<<(B_ * N_) / 16, TPB, 0, stream>>>(xnt, ci, idx);
    transpose_bf16_kernel<<<B_ * 16, TPB, 0, stream>>>(x, xtb);  // xnb dead now
    conv_mfma_kernel<<<B_ * 8, TPB, 0, stream>>>(xtb, wbh, wbl, idx, out);
}

// Round 14
// 156.633 us; speedup vs baseline: 4.7083x; 1.0070x over previous
//
#include <hip/hip_runtime.h>
#include <hip/hip_bf16.h>

#define TPB 256

typedef float f32x4 __attribute__((ext_vector_type(4)));
typedef short s16x8 __attribute__((ext_vector_type(8)));

static constexpr int B_ = 32;
static constexpr int C_ = 128;
static constexpr int N_ = 1024;
static constexpr int K_ = 9;
static constexpr int CN_ = C_ * N_;
static constexpr float INFV = 1.0e10f;
static constexpr float EPS_ = 1e-8f;

// ws layout (float slots)
static constexpr size_t XNT_OFF = 0;                             // xnt [B][N][C] fp32
static constexpr size_t XNB_OFF = (size_t)B_ * CN_;              // xnb [B][N][C] bf16 (xtb aliases later)
static constexpr size_t WBH_OFF = XNB_OFF + (size_t)B_ * CN_ / 2;
static constexpr size_t WBL_OFF = WBH_OFF + (size_t)K_ * C_ * C_ / 2;
static constexpr size_t CI_OFF  = WBL_OFF + (size_t)K_ * C_ * C_ / 2;  // [B][N][16] int
static constexpr size_t IDX_OFF = CI_OFF + (size_t)B_ * N_ * 16;       // [B][N][9] int

__device__ __forceinline__ void gload_lds16(const void* g, void* l) {
    __builtin_amdgcn_global_load_lds((const __attribute__((address_space(1))) void*)g,
                                     (__attribute__((address_space(3))) void*)l, 16, 0, 0);
}

// exact stable top-9 insert (rescore only)
#define INSERT9(Vv, Ii, vexpr, gmexpr)                                      \
    {                                                                       \
        float _v = (vexpr); int _gm = (gmexpr);                             \
        bool bp[9];                                                         \
        _Pragma("unroll")                                                   \
        for (int _p = 0; _p < 9; ++_p)                                      \
            bp[_p] = (_v > Vv[_p]) || (_v == Vv[_p] && _gm < Ii[_p]);       \
        if (bp[8]) {                                                        \
            _Pragma("unroll")                                               \
            for (int _p = 8; _p >= 1; --_p) {                               \
                Vv[_p] = bp[_p - 1] ? Vv[_p - 1] : (bp[_p] ? _v  : Vv[_p]); \
                Ii[_p] = bp[_p - 1] ? Ii[_p - 1] : (bp[_p] ? _gm : Ii[_p]); \
            }                                                               \
            if (bp[0]) { Vv[0] = _v; Ii[0] = _gm; }                         \
        }                                                                   \
    }

__device__ __forceinline__ unsigned umin3(unsigned a, unsigned b, unsigned c) {
    return min(min(a, b), c);                  // expect v_min3_u32
}

// unsorted top-16 keyset insert: replace unique min slot, min3-structured tree
#define KINSERT16(KEYS, THR, KEXPR)                                         \
    {                                                                       \
        unsigned _k = (KEXPR);                                              \
        if (_k > (THR)) {                                                   \
            _Pragma("unroll")                                               \
            for (int _p = 0; _p < 16; ++_p)                                 \
                KEYS[_p] = (KEYS[_p] == (THR)) ? _k : KEYS[_p];             \
            unsigned _m0 = umin3(KEYS[0],  KEYS[1],  KEYS[2]);              \
            unsigned _m1 = umin3(KEYS[3],  KEYS[4],  KEYS[5]);              \
            unsigned _m2 = umin3(KEYS[6],  KEYS[7],  KEYS[8]);              \
            unsigned _m3 = umin3(KEYS[9],  KEYS[10], KEYS[11]);             \
            unsigned _m4 = umin3(KEYS[12], KEYS[13], KEYS[14]);             \
            (THR) = min(umin3(_m0, _m1, _m2), umin3(_m3, _m4, KEYS[15]));   \
        }                                                                   \
    }

// monotone (value, smaller-index-wins) packed key; drops 10 low mantissa bits
// of the RAW float (fine steps at top-sim exponents) — r10/r12-proven form
__device__ __forceinline__ unsigned simkey(float v, unsigned lowfield) {
    unsigned u = __float_as_uint(v);
    u ^= ((unsigned)((int)u >> 31) | 0x80000000u);
    return (u & 0xFFFFFC00u) | lowfield;
}

// ---------------------------------------------------------------------------
// 1) normtrans: xnt[b][n][c] = x[b][c][n]/(||x[:,n]||+eps) fp32; xnb = bf16(same)
// ---------------------------------------------------------------------------
__global__ __launch_bounds__(TPB) void normtrans_kernel(const float* __restrict__ x,
                                                        float* __restrict__ xnt,
                                                        __hip_bfloat16* __restrict__ xnb) {
    __shared__ float lds[128][65];
    __shared__ float nrm[64];
    int b = blockIdx.x >> 4, n0 = (blockIdx.x & 15) << 6;
    const float* src = x + (size_t)b * CN_ + n0;
    #pragma unroll 4
    for (int i = 0; i < 32; ++i) {
        int flat = i * TPB + threadIdx.x;
        int c = flat >> 6, nn = flat & 63;
        lds[c][nn] = src[(size_t)c * N_ + nn];
    }
    __syncthreads();
    if (threadIdx.x < 64) {
        float ss = 0.f;
        #pragma unroll 8
        for (int c = 0; c < C_; ++c) { float v = lds[c][threadIdx.x]; ss += v * v; }
        nrm[threadIdx.x] = sqrtf(ss) + EPS_;
    }
    __syncthreads();
    float* dstf = xnt + ((size_t)b * N_ + n0) * C_;
    __hip_bfloat16* dstb = xnb + ((size_t)b * N_ + n0) * C_;
    #pragma unroll 4
    for (int i = 0; i < 32; ++i) {
        int flat = i * TPB + threadIdx.x;
        int nn = flat >> 7, c = flat & 127;
        float v = lds[c][nn] / nrm[nn];
        dstf[(size_t)nn * C_ + c] = v;
        dstb[(size_t)nn * C_ + c] = __float2bfloat16(v);
    }
}

// ---------------------------------------------------------------------------
// 2) xtb[b][n][c] = bf16(x[b][c][n])   (raw features for conv gather)
// ---------------------------------------------------------------------------
__global__ __launch_bounds__(TPB) void transpose_bf16_kernel(const float* __restrict__ x,
                                                             __hip_bfloat16* __restrict__ xtb) {
    __shared__ float lds[128][65];
    int b = blockIdx.x >> 4, n0 = (blockIdx.x & 15) << 6;
    const float* src = x + (size_t)b * CN_ + n0;
    #pragma unroll 4
    for (int i = 0; i < 32; ++i) {
        int flat = i * TPB + threadIdx.x;
        int c = flat >> 6, nn = flat & 63;
        lds[c][nn] = src[(size_t)c * N_ + nn];
    }
    __syncthreads();
    __hip_bfloat16* dst = xtb + (size_t)b * CN_ + (size_t)n0 * C_;
    #pragma unroll 4
    for (int i = 0; i < 32; ++i) {
        int flat = i * TPB + threadIdx.x;
        int nn = flat >> 7, c = flat & 127;
        dst[(size_t)nn * C_ + c] = __float2bfloat16(lds[c][nn]);
    }
}

// ---------------------------------------------------------------------------
// 3) split-bf16 weights: wh/wl [k][o][c]
// ---------------------------------------------------------------------------
__global__ __launch_bounds__(TPB) void wbprep_kernel(const float* __restrict__ W,
                                                     __hip_bfloat16* __restrict__ wh,
                                                     __hip_bfloat16* __restrict__ wl) {
    int t = blockIdx.x * TPB + threadIdx.x;
    int k = t / (C_ * C_);
    int r = t - k * (C_ * C_);
    int o = r >> 7, c = r & 127;
    float w = W[((size_t)o * C_ + c) * K_ + k];
    __hip_bfloat16 h = __float2bfloat16(w);
    wh[t] = h;
    wl[t] = __float2bfloat16(w - __bfloat162float(h));
}

// ---------------------------------------------------------------------------
// 4) phase-1: swapped-operand MFMA sim, register-direct top-16 keyset scan.
//    Block = (b, 32-row tile), 256 thr, 4 waves: (rb = wv&1, ch = wv>>1).
//    LDS 40960 B -> 4 blocks/CU. Grid 1024. Keyset/simkey = r12-proven.
// ---------------------------------------------------------------------------
__global__ __launch_bounds__(TPB, 4) void sim_mfma_topk_kernel(const __hip_bfloat16* __restrict__ xnb,
                                                               int* __restrict__ ci) {
    __shared__ __align__(16) ushort SH[4096 + 16384];   // Ab [2][32*64] | Bb [2][128*64]
    ushort* Ab = SH;                                    // mbuf (u32) aliases Ab at merge
    ushort* Bb = SH + 4096;

    const int tid = threadIdx.x;
    const int lane = tid & 63;
    const int wv = tid >> 6;                  // 0..3
    const int rb = wv & 1;                    // 16-row block within the 32-row tile
    const int ch = wv >> 1;                   // col half (64 cols of each 128-tile)
    const int b  = blockIdx.x >> 5;
    const int n0 = (blockIdx.x & 31) << 5;    // 32 rows per block
    const __hip_bfloat16* xb = xnb + (size_t)b * CN_;
    const int l15 = lane & 15, l7 = lane & 7, lq = lane >> 4;
    const int swz = ((lane & 7) ^ (lane >> 3)) * 8;
    const int grow = n0 + 16 * rb + l15;      // the row this lane selects for

    // stage Ab (32 rows x 128c, 2 halves): 8 gll units, 2 per wave
    #pragma unroll
    for (int q = 0; q < 2; ++q) {
        int u = 2 * wv + q;
        int hh = u >> 2, r0 = (u & 3) * 8;
        gload_lds16(xb + (size_t)(n0 + r0 + (lane >> 3)) * C_ + hh * 64 + swz,
                    Ab + hh * 2048 + r0 * 64);
    }
    // stage Bb tile 0 (tokens 0..127): 32 units, 8 per wave
    #pragma unroll
    for (int q = 0; q < 8; ++q) {
        int u = 8 * wv + q;
        int hh = u >> 4, r0 = (u & 15) * 8;
        gload_lds16(xb + (size_t)(r0 + (lane >> 3)) * C_ + hh * 64 + swz,
                    Bb + hh * 8192 + r0 * 64);
    }
    __syncthreads();

    // row fragments (B-operand of the swapped MFMA), constant across all mt
    s16x8 af[2][2];
    #pragma unroll
    for (int h = 0; h < 2; ++h)
        #pragma unroll
        for (int kc = 0; kc < 2; ++kc)
            af[h][kc] = *(const s16x8*)&Ab[h * 2048 + (16 * rb + l15) * 64 + (((kc * 4 + lq) ^ l7) << 3)];

    unsigned keys[16];
    #pragma unroll
    for (int p = 0; p < 16; ++p) keys[p] = (unsigned)p;   // distinct, below any real key
    unsigned thr = 0u;

    #pragma unroll 1
    for (int mt = 0; mt < 8; ++mt) {
        f32x4 acc[4];
        #pragma unroll
        for (int t = 0; t < 4; ++t) acc[t] = (f32x4){0.f, 0.f, 0.f, 0.f};

        #pragma unroll
        for (int h = 0; h < 2; ++h)
            #pragma unroll
            for (int kc = 0; kc < 2; ++kc) {
                const int phys = ((kc * 4 + lq) ^ l7) << 3;
                #pragma unroll
                for (int t = 0; t < 4; ++t) {
                    s16x8 bb = *(const s16x8*)&Bb[h * 8192 + (64 * ch + 16 * t + l15) * 64 + phys];
                    // SWAPPED operands: A = col fragment, B = row fragment
                    acc[t] = __builtin_amdgcn_mfma_f32_16x16x32_bf16(bb, af[h][kc], acc[t], 0, 0, 0);
                }
            }
        __syncthreads();                      // all MFMA reads of Bb done

        if (mt < 7) {                         // stage next 128 tokens
            #pragma unroll
            for (int q = 0; q < 8; ++q) {
                int u = 8 * wv + q;
                int hh = u >> 4, r0 = (u & 15) * 8;
                gload_lds16(xb + (size_t)(128 * (mt + 1) + r0 + (lane >> 3)) * C_ + hh * 64 + swz,
                            Bb + hh * 8192 + r0 * 64);
            }
        }

        // register-direct scan: lane owns row grow; cols = mt*128+64ch+4lq+16t+r
        const int colb = (mt << 7) + 64 * ch + 4 * lq;
        #pragma unroll
        for (int t = 0; t < 4; ++t)
            #pragma unroll
            for (int r = 0; r < 4; ++r) {
                int gcol = colb + 16 * t + r;
                float v = acc[t][r];
                if (gcol == grow) v = INFV;   // self always a candidate
                KINSERT16(keys, thr, simkey(v, 1023u - (unsigned)gcol))
            }
        __syncthreads();                      // drains gll: next Bb ready
    }

    // merge the 4 lq lanes (snapshot BEFORE insert: in-place shfl merge is a
    // read-during-mutation hazard; partner col-sets are disjoint at both steps)
    #pragma unroll
    for (int d = 16; d <= 32; d <<= 1) {
        unsigned inc[16];
        #pragma unroll
        for (int p = 0; p < 16; ++p)
            inc[p] = (unsigned)__shfl_xor((int)keys[p], d);
        #pragma unroll
        for (int p = 0; p < 16; ++p) KINSERT16(keys, thr, inc[p])
    }

    // cross-wave merge (col half 1 -> half 0) via small LDS buffer over Ab
    unsigned* mbuf = (unsigned*)SH;           // [32 rows][16 keys]
    if (ch == 1 && lq == 0) {
        #pragma unroll
        for (int p = 0; p < 16; ++p) mbuf[(16 * rb + l15) * 16 + p] = keys[p];
    }
    __syncthreads();
    if (ch == 0 && lq == 0) {
        #pragma unroll
        for (int p = 0; p < 16; ++p) KINSERT16(keys, thr, mbuf[(16 * rb + l15) * 16 + p])
        int* op = ci + ((size_t)b * N_ + grow) * 16;
        #pragma unroll
        for (int p = 0; p < 16; ++p) op[p] = 1023 - (int)(keys[p] & 1023u);
    }
}

// ---------------------------------------------------------------------------
// 5) rescore: exact fp32 dots of the 16 candidates -> stable top-9 indices
// ---------------------------------------------------------------------------
__global__ __launch_bounds__(TPB) void rescore_kernel(const float* __restrict__ xnt,
                                                      const int* __restrict__ ci,
                                                      int* __restrict__ idxo) {
    const int tid = threadIdx.x;
    const int g = tid >> 4, l = tid & 15;
    const size_t row = (size_t)blockIdx.x * 16 + g;       // global row 0..32767
    const int nrow = (int)(row & (N_ - 1));               // token index within batch
    const float* xbase = xnt + (row >> 10) * (size_t)CN_; // batch base
    const float* rvp = xbase + (size_t)nrow * C_;

    float rv[8];
    #pragma unroll
    for (int t = 0; t < 8; ++t) rv[t] = rvp[t * 16 + l];

    float val[9]; int id[9];
    #pragma unroll
    for (int p = 0; p < 9; ++p) { val[p] = -1e30f; id[p] = -1; }

    const int* cp = ci + row * 16;
    #pragma unroll 4
    for (int j = 0; j < 16; ++j) {
        int cand = cp[j];
        const float* cv = xbase + (size_t)cand * C_;
        float s = 0.f;
        #pragma unroll
        for (int t = 0; t < 8; ++t) s = fmaf(rv[t], cv[t * 16 + l], s);
        #pragma unroll
        for (int d = 1; d < 16; d <<= 1) s += __shfl_xor(s, d);
        float v = (cand == nrow) ? INFV : s;
        INSERT9(val, id, v, cand)
    }
    if (l == 0) {
        int* op = idxo + row * 9;
        #pragma unroll
        for (int p = 0; p < 9; ++p) op[p] = id[p];
    }
}

// ---------------------------------------------------------------------------
// 6) MFMA conv (unchanged, passing): 128o x 128n per block
// ---------------------------------------------------------------------------
__global__ __launch_bounds__(TPB) void conv_mfma_kernel(const __hip_bfloat16* __restrict__ xtb,
                                                        const __hip_bfloat16* __restrict__ wbh,
                                                        const __hip_bfloat16* __restrict__ wbl,
                                                        const int* __restrict__ idxi,
                                                        float* __restrict__ out) {
    __shared__ __align__(16) __hip_bfloat16 gbuf[2][128 * 64];
    __shared__ __align__(16) __hip_bfloat16 hbuf[2][128 * 64];
    __shared__ __align__(16) __hip_bfloat16 lbuf[2][128 * 64];
    __shared__ int ids[K_ * 128];

    const int tid = threadIdx.x;
    const int lane = tid & 63;
    const int wv = tid >> 6;
    const int b  = blockIdx.x >> 3;
    const int n0 = (blockIdx.x & 7) << 7;
    const __hip_bfloat16* xb = xtb + (size_t)b * CN_;

    for (int j = tid; j < K_ * 128; j += TPB) {
        int k = j >> 7, r = j & 127;
        ids[j] = idxi[((size_t)b * N_ + n0 + r) * K_ + k];
    }
    __syncthreads();

    f32x4 acc[2][8];
    #pragma unroll
    for (int mt = 0; mt < 2; ++mt)
        #pragma unroll
        for (int nt = 0; nt < 8; ++nt) acc[mt][nt] = (f32x4){0.f, 0.f, 0.f, 0.f};

    const int swz = ((lane & 7) ^ (lane >> 3)) * 8;

#define CONV_STAGE(S, PB)                                                               \
    {                                                                                   \
        const int k_ = (S) >> 1, ch_ = ((S) & 1) * 64;                                  \
        _Pragma("unroll")                                                               \
        for (int q_ = 0; q_ < 4; ++q_) {                                                \
            int row_ = 32 * wv + 8 * q_ + (lane >> 3);                                  \
            int tok_ = ids[k_ * 128 + row_];                                            \
            gload_lds16(xb + (size_t)tok_ * C_ + ch_ + swz, &gbuf[PB][(32 * wv + 8 * q_) * 64]); \
            const size_t wr_ = ((size_t)k_ * 128 + row_) * C_ + ch_ + swz;              \
            gload_lds16(wbh + wr_, &hbuf[PB][(32 * wv + 8 * q_) * 64]);                 \
            gload_lds16(wbl + wr_, &lbuf[PB][(32 * wv + 8 * q_) * 64]);                 \
        }                                                                               \
    }

    CONV_STAGE(0, 0)
    __syncthreads();

    const int l15 = lane & 15, l7 = lane & 7, lq = lane >> 4;
    int pb = 0;
    #pragma unroll 1
    for (int s = 0; s < 18; ++s) {
        if (s < 17) CONV_STAGE(s + 1, pb ^ 1)
        const __hip_bfloat16* G = gbuf[pb];
        const __hip_bfloat16* H = hbuf[pb];
        const __hip_bfloat16* L = lbuf[pb];
        #pragma unroll
        for (int kc = 0; kc < 2; ++kc) {
            const int phys = ((kc * 4 + lq) ^ l7) * 8;
            s16x8 bb[8];
            #pragma unroll
            for (int nt = 0; nt < 8; ++nt)
                bb[nt] = *(const s16x8*)&G[(16 * nt + l15) * 64 + phys];
            #pragma unroll
            for (int mt = 0; mt < 2; ++mt) {
                const int orow = (32 * wv + 16 * mt + l15) * 64 + phys;
                s16x8 ah = *(const s16x8*)&H[orow];
                s16x8 al = *(const s16x8*)&L[orow];
                #pragma unroll
                for (int nt = 0; nt < 8; ++nt) {
                    acc[mt][nt] = __builtin_amdgcn_mfma_f32_16x16x32_bf16(ah, bb[nt], acc[mt][nt], 0, 0, 0);
                    acc[mt][nt] = __builtin_amdgcn_mfma_f32_16x16x32_bf16(al, bb[nt], acc[mt][nt], 0, 0, 0);
                }
            }
        }
        __syncthreads();
        pb ^= 1;
    }

    float* ob = out + (size_t)b * CN_;
    #pragma unroll
    for (int mt = 0; mt < 2; ++mt)
        #pragma unroll
        for (int nt = 0; nt < 8; ++nt) {
            int o = 32 * wv + 16 * mt + lq * 4;
            int n = n0 + 16 * nt + l15;
            #pragma unroll
            for (int r = 0; r < 4; ++r)
                ob[(size_t)(o + r) * N_ + n] = acc[mt][nt][r];
        }
#undef CONV_STAGE
}

// ---------------------------------------------------------------------------
extern "C" void kernel_launch(void* const* d_in, const int* in_sizes, int n_in,
                              void* d_out, int out_size, void* d_ws, size_t ws_size,
                              hipStream_t stream) {
    (void)in_sizes; (void)n_in; (void)out_size; (void)ws_size;
    const float* x = (const float*)d_in[0];
    const float* W = (const float*)d_in[1];
    float* out = (float*)d_out;
    float* ws  = (float*)d_ws;

    float* xnt = ws + XNT_OFF;
    __hip_bfloat16* xnb = (__hip_bfloat16*)(ws + XNB_OFF);
    __hip_bfloat16* xtb = (__hip_bfloat16*)(ws + XNB_OFF);  // aliases xnb (disjoint lifetime)
    __hip_bfloat16* wbh = (__hip_bfloat16*)(ws + WBH_OFF);
    __hip_bfloat16* wbl = (__hip_bfloat16*)(ws + WBL_OFF);
    int* ci  = (int*)(ws + CI_OFF);
    int* idx = (int*)(ws + IDX_OFF);

    normtrans_kernel<<<B_ * 16, TPB, 0, stream>>>(x, xnt, xnb);
    wbprep_kernel<<<(K_ * C_ * C_) / TPB, TPB, 0, stream>>>(W, wbh, wbl);
    sim_mfma_topk_kernel<<<B_ * 32, TPB, 0, stream>>>(xnb, ci);
    rescore_kernel<<<(B_ * N_) / 16, TPB, 0, stream>>>(xnt, ci, idx);
    transpose_bf16_kernel<<<B_ * 16, TPB, 0, stream>>>(x, xtb);  // xnb dead now
    conv_mfma_kernel<<<B_ * 8, TPB, 0, stream>>>(xtb, wbh, wbl, idx, out);
}